// Round 14
// baseline (1109.705 us; speedup 1.0000x reference)
//
#include <hip/hip_runtime.h>
#include <hip/hip_fp16.h>

#define D 128
#define DE 16
#define NL 4
#define EPSV 1e-5f
#define S_U1 8
#define S_U2 4
#define NBMSG 512      // msg persistent blocks (2/CU, LDS-limited)
#define MSG_LDS 75776  // 8K We + 32K W2 + 8*4352 zeb

using f32x4  = __attribute__((ext_vector_type(4))) float;
using bf16x8 = __attribute__((ext_vector_type(8))) short;
typedef _Float16 f16x8 __attribute__((ext_vector_type(8)));

#define MFMAB(a, b, c) __builtin_amdgcn_mfma_f32_16x16x32_bf16((a), (b), (c), 0, 0, 0)
#define MFMAH(a, b, c) __builtin_amdgcn_mfma_f32_16x16x32_f16((a), (b), (c), 0, 0, 0)

union H8 { int4 i; unsigned int u[4]; f16x8 f; };

__device__ __forceinline__ unsigned short f2bf(float x) {
  unsigned int u = __float_as_uint(x);
  u = (u + 0x7FFFu + ((u >> 16) & 1u)) >> 16;  // RNE
  return (unsigned short)u;
}

__device__ __forceinline__ unsigned short f2h(float x) {
  return __half_as_ushort(__float2half(x));
}

// packed f16 math via VOP3P inline asm (validated R9-R13)
__device__ __forceinline__ unsigned int pk_add(unsigned int a, unsigned int b) {
  unsigned int r;
  asm("v_pk_add_f16 %0, %1, %2" : "=v"(r) : "v"(a), "v"(b));
  return r;
}
__device__ __forceinline__ unsigned int pk_relu(unsigned int a) {
  unsigned int r;
  asm("v_pk_max_f16 %0, %1, 0" : "=v"(r) : "v"(a));
  return r;
}

// CONTRACT (m104/m108): LDS dest = wave-uniform base + lane*16. Call sites MUST
// use idx = i*blockDim + tid so consecutive lanes write consecutive granules.
__device__ __forceinline__ void gload_lds16(const void* gp, void* lp) {
  typedef __attribute__((address_space(1))) unsigned int as1_u32;
  typedef __attribute__((address_space(3))) unsigned int as3_u32;
  __builtin_amdgcn_global_load_lds((as1_u32*)(unsigned long long)gp,
                                   (as3_u32*)(unsigned int)(unsigned long long)lp,
                                   16, 0, 0);
}

__device__ __forceinline__ bf16x8 pack8(float4 a, float4 b) {
  bf16x8 o;
  o[0] = (short)f2bf(a.x); o[1] = (short)f2bf(a.y);
  o[2] = (short)f2bf(a.z); o[3] = (short)f2bf(a.w);
  o[4] = (short)f2bf(b.x); o[5] = (short)f2bf(b.y);
  o[6] = (short)f2bf(b.z); o[7] = (short)f2bf(b.w);
  return o;
}

__device__ __forceinline__ int4 pack8h(float4 a, float4 b) {
  int4 o;
  o.x = (int)((unsigned)f2h(a.x) | ((unsigned)f2h(a.y) << 16));
  o.y = (int)((unsigned)f2h(a.z) | ((unsigned)f2h(a.w) << 16));
  o.z = (int)((unsigned)f2h(b.x) | ((unsigned)f2h(b.y) << 16));
  o.w = (int)((unsigned)f2h(b.z) | ((unsigned)f2h(b.w) << 16));
  return o;
}

// ---------------- prep kernels (validated) ----------------
__global__ void wprep_kernel(const float* __restrict__ W, const float* __restrict__ g,
                             const float* __restrict__ v, unsigned short* __restrict__ out,
                             int K, int S, int total) {
  int idx = blockIdx.x * 256 + threadIdx.x;
  if (idx >= total) return;
  int e = idx & 7, l0 = (idx >> 3) & 63, f = idx >> 9;
  int n = f & 7, sf = f >> 3, s = sf % S, l = sf / S;
  int k = s * 32 + ((l0 >> 4) << 3) + e;
  int c = (n << 4) + (l0 & 15);
  float val = 0.f;
  if (k < K) {
    float sc = g[l * D + c] * rsqrtf(v[l * D + c] + EPSV);
    val = W[((size_t)(l * K + k)) * D + c] * sc;
  }
  out[idx] = f2bf(val);
}

__global__ void wprep16_kernel(const float* __restrict__ W, const float* __restrict__ g,
                               const float* __restrict__ v, unsigned short* __restrict__ out,
                               int Ktot, int ko, int Kact, int S, int total) {
  int idx = blockIdx.x * 256 + threadIdx.x;
  if (idx >= total) return;
  int e = idx & 7, l0 = (idx >> 3) & 63, f = idx >> 9;
  int n = f & 7, sf = f >> 3, s = sf % S, l = sf / S;
  int k = s * 32 + ((l0 >> 4) << 3) + e;
  int c = (n << 4) + (l0 & 15);
  float val = 0.f;
  if (k < Kact) {
    float sc = g[l * D + c] * rsqrtf(v[l * D + c] + EPSV);
    val = W[((size_t)(l * Ktot + ko + k)) * D + c] * sc;
  }
  out[idx] = f2h(val);
}

__global__ void wprepz_kernel(const float* __restrict__ W1, const float* __restrict__ g,
                              const float* __restrict__ v, unsigned short* __restrict__ out,
                              int total) {
  int idx = blockIdx.x * 256 + threadIdx.x;
  if (idx >= total) return;
  int e = idx & 7, l0 = (idx >> 3) & 63, f = idx >> 9;
  int n = f & 15, sf = f >> 4, s = sf & 3, l = sf >> 2;
  int k = s * 32 + ((l0 >> 4) << 3) + e;
  int c = ((n & 7) << 4) + (l0 & 15);
  int row = (n < 8) ? k : 128 + k;
  float sc = g[l * D + c] * rsqrtf(v[l * D + c] + EPSV);
  float val = W1[((size_t)(l * 272 + row)) * D + c] * sc;
  out[idx] = f2bf(val);
}

// Win frag-order, K=64 (S=2), no BN fold
__global__ void wprepx_kernel(const float* __restrict__ Win, unsigned short* __restrict__ out) {
  int idx = blockIdx.x * 256 + threadIdx.x;
  if (idx >= 8192) return;
  int e = idx & 7, l0 = (idx >> 3) & 63, f = idx >> 9;
  int n = f & 7, s = f >> 3;
  int k = s * 32 + ((l0 >> 4) << 3) + e;
  int c = (n << 4) + (l0 & 15);
  out[idx] = f2bf(Win[k * D + c]);
}

__global__ void cvtx_kernel(const float* __restrict__ x, unsigned short* __restrict__ xbf, int n8) {
  int idx = blockIdx.x * 256 + threadIdx.x;
  if (idx >= n8) return;
  float4 a = reinterpret_cast<const float4*>(x)[idx * 2];
  float4 b = reinterpret_cast<const float4*>(x)[idx * 2 + 1];
  reinterpret_cast<bf16x8*>(xbf)[idx] = pack8(a, b);
}

__global__ void bprep_kernel(const float* __restrict__ b, const float* __restrict__ g,
                             const float* __restrict__ be, const float* __restrict__ m,
                             const float* __restrict__ v, float* __restrict__ out) {
  int idx = blockIdx.x * 256 + threadIdx.x;
  if (idx >= NL * D) return;
  float s = g[idx] * rsqrtf(v[idx] + EPSV);
  out[idx] = (b[idx] - m[idx]) * s + be[idx];
}

// agg f32 -> bf16 (keeps node's operand path identical to R12/R13)
__global__ void agg2bf_kernel(const float* __restrict__ agg, unsigned short* __restrict__ aggbf, int n8) {
  int idx = blockIdx.x * 256 + threadIdx.x;
  if (idx >= n8) return;
  float4 a = reinterpret_cast<const float4*>(agg)[idx * 2];
  float4 b = reinterpret_cast<const float4*>(agg)[idx * 2 + 1];
  reinterpret_cast<bf16x8*>(aggbf)[idx] = pack8(a, b);
}

// ---------------- fused xproj + layer-0 z-GEMM (validated R12/R13) ----------------
__global__ __launch_bounds__(256)
void xz_kernel(const unsigned short* __restrict__ xbf,
               const unsigned short* __restrict__ Wxf,
               const float* __restrict__ bin,
               const unsigned short* __restrict__ Wzf,
               const float* __restrict__ b1,
               float* __restrict__ h,
               unsigned short* __restrict__ hbf,
               unsigned short* __restrict__ zds, int N) {
  __shared__ unsigned short m1ls[4][16 * 128];
  const int tid = threadIdx.x, wid = tid >> 6, lane = tid & 63, g = lane >> 4, r = lane & 15;
  const int nbase = blockIdx.x * 64;
  const int nr = nbase + wid * 16 + r;
  const int ar = (nr < N) ? nr : (N - 1);

  bf16x8 aX[2];
#pragma unroll
  for (int s = 0; s < 2; ++s)
    aX[s] = *reinterpret_cast<const bf16x8*>(xbf + (size_t)ar * 64 + s * 32 + g * 8);

  f32x4 acc[8];
#pragma unroll
  for (int n = 0; n < 8; ++n)
#pragma unroll
    for (int q = 0; q < 4; ++q) acc[n][q] = 0.f;
#pragma unroll
  for (int s = 0; s < 2; ++s)
#pragma unroll
    for (int n = 0; n < 8; ++n)
      acc[n] = MFMAB(aX[s], *reinterpret_cast<const bf16x8*>(Wxf + (((s * 8 + n) << 9) + (lane << 3))), acc[n]);

  float bia[8];
#pragma unroll
  for (int n = 0; n < 8; ++n) bia[n] = bin[n * 16 + r];

  unsigned short* m1w = &m1ls[wid][0];
#pragma unroll
  for (int j = 0; j < 4; ++j) {
    int node = nbase + wid * 16 + g * 4 + j;
    if (node < N) {
#pragma unroll
      for (int n = 0; n < 8; ++n) {
        int col = n * 16 + r;
        float hv = acc[n][j] + bia[n];
        h[(size_t)node * D + col] = hv;
        unsigned short hb = f2bf(hv);
        hbf[(size_t)node * D + col] = hb;
        int row0 = g * 4 + j;
        m1w[row0 * 128 + (col ^ ((row0 & 7) << 3))] = hb;
      }
    }
  }

  bf16x8 aZ[4];
#pragma unroll
  for (int s = 0; s < 4; ++s) {
    int k0 = s * 32 + g * 8;
    aZ[s] = *reinterpret_cast<const bf16x8*>(m1w + r * 128 + (k0 ^ ((r & 7) << 3)));
  }
  float bz[8];
#pragma unroll
  for (int n = 0; n < 8; ++n) bz[n] = b1[n * 16 + r];
#pragma unroll
  for (int half = 0; half < 2; ++half) {
    f32x4 zacc[8];
#pragma unroll
    for (int n = 0; n < 8; ++n)
#pragma unroll
      for (int q = 0; q < 4; ++q) zacc[n][q] = 0.f;
#pragma unroll
    for (int s = 0; s < 4; ++s)
#pragma unroll
      for (int n = 0; n < 8; ++n)
        zacc[n] = MFMAB(aZ[s], *reinterpret_cast<const bf16x8*>(Wzf + (((s * 16 + half * 8 + n) << 9) + (lane << 3))), zacc[n]);
#pragma unroll
    for (int n = 0; n < 8; ++n)
#pragma unroll
      for (int j = 0; j < 4; ++j) {
        int node = nbase + wid * 16 + g * 4 + j;
        if (node < N) {
          float v = zacc[n][j] + (half == 0 ? bz[n] : 0.f);
          zds[(size_t)node * 256 + (half * 8 + n) * 16 + r] = f2h(v);
        }
      }
  }
}

// ---------------- counting sort of edges by dst (validated) ----------------
__global__ void hist_kernel(const int* __restrict__ eidx, int* __restrict__ hist, int E) {
  int e = blockIdx.x * 256 + threadIdx.x;
  if (e < E) atomicAdd(&hist[eidx[E + e]], 1);
}

__global__ void scan1_kernel(const int* __restrict__ hist, int* __restrict__ bsum, int N) {
  __shared__ int sb[256];
  int i = blockIdx.x * 256 + threadIdx.x;
  sb[threadIdx.x] = (i < N) ? hist[i] : 0;
  __syncthreads();
  for (int d = 128; d > 0; d >>= 1) {
    if (threadIdx.x < d) sb[threadIdx.x] += sb[threadIdx.x + d];
    __syncthreads();
  }
  if (threadIdx.x == 0) bsum[blockIdx.x] = sb[0];
}

__global__ void scan2_kernel(int* __restrict__ bsum, int nb) {
  __shared__ int sb[2][256];
  int t = threadIdx.x;
  int v = (t < nb) ? bsum[t] : 0;
  int p = 0;
  sb[0][t] = v; __syncthreads();
#pragma unroll
  for (int d = 1; d < 256; d <<= 1) {
    int nv = sb[p][t] + ((t >= d) ? sb[p][t - d] : 0);
    sb[p ^ 1][t] = nv; p ^= 1;
    __syncthreads();
  }
  if (t < nb) bsum[t] = sb[p][t] - v;
}

__global__ void scan3_kernel(int* __restrict__ hist, const int* __restrict__ bsum, int N) {
  __shared__ int sb[2][256];
  int i = blockIdx.x * 256 + threadIdx.x, t = threadIdx.x;
  int v = (i < N) ? hist[i] : 0;
  int p = 0;
  sb[0][t] = v; __syncthreads();
#pragma unroll
  for (int d = 1; d < 256; d <<= 1) {
    int nv = sb[p][t] + ((t >= d) ? sb[p][t - d] : 0);
    sb[p ^ 1][t] = nv; p ^= 1;
    __syncthreads();
  }
  if (i < N) hist[i] = sb[p][t] - v + bsum[blockIdx.x];
}

__global__ void scatter_kernel(const int* __restrict__ eidx, int* __restrict__ cursor,
                               int* __restrict__ dstS, int* __restrict__ srcS,
                               int* __restrict__ eidS, int E) {
  int e = blockIdx.x * 256 + threadIdx.x;
  if (e >= E) return;
  int d = eidx[E + e];
  int pos = atomicAdd(&cursor[d], 1);
  dstS[pos] = d;
  srcS[pos] = eidx[e];
  eidS[pos] = e;
}

__global__ void eperm_kernel(const float* __restrict__ eattr, const int* __restrict__ eidS,
                             unsigned short* __restrict__ ebfS, int E) {
  int i = blockIdx.x * 256 + threadIdx.x;
  if (i >= E) return;
  const float4* src = reinterpret_cast<const float4*>(eattr + (size_t)eidS[i] * DE);
  *reinterpret_cast<int4*>(ebfS + (size_t)i * DE) = pack8h(src[0], src[1]);
  *reinterpret_cast<int4*>(ebfS + (size_t)i * DE + 8) = pack8h(src[2], src[3]);
}

// ---------------- fused message kernel: ze in-kernel + run-compressed atomic reduce ----------------
// dst-sorted edges + contiguous block chunks => atomics land in the local XCD L2
// (per-XCD agg footprint ~3.2MB <= 4MB). Replaces msgb store + reduce_kernel.
__global__ __launch_bounds__(512, 4)
void msg_kernel(const unsigned short* __restrict__ zds,
                const unsigned short* __restrict__ ebfS,
                const int* __restrict__ dstS,
                const int* __restrict__ srcS,
                const unsigned short* __restrict__ Wef,   // f16 frag, 8KB
                const unsigned short* __restrict__ W2f,   // f16 frag, 32KB
                const float* __restrict__ b2,
                float* __restrict__ agg, int E, int T) {
  extern __shared__ char smem[];
  unsigned short* Wels = (unsigned short*)smem;            // We: [0, 4096) shorts
  unsigned short* W2ls = (unsigned short*)(smem + 8192);   // W2: 16384 shorts
  const int tid = threadIdx.x;
  const int wid = tid >> 6, lane = tid & 63, g = lane >> 4, r = lane & 15;
  unsigned short* zeb = (unsigned short*)(smem + 40960 + wid * 4352);  // 16x136 shorts/wave

  gload_lds16(Wef + ((size_t)tid << 3), smem + (tid << 4));
#pragma unroll
  for (int i = 0; i < 4; ++i) {
    int idx = i * 512 + tid;
    gload_lds16(W2f + ((size_t)idx << 3), smem + 8192 + (idx << 4));
  }

  float bia2[8];
#pragma unroll
  for (int n = 0; n < 8; ++n) bia2[n] = b2[n * 16 + r];

  const int t0 = (int)(((long long)blockIdx.x * T) / gridDim.x);
  const int t1 = (int)(((long long)(blockIdx.x + 1) * T) / gridDim.x);

  __syncthreads();

  for (int t = t0; t < t1; ++t) {
    const int p0 = t * 128 + wid * 16 + r;
    const int ii0 = min(p0, E - 1);
    const int dst0 = dstS[ii0], src0 = srcS[ii0];

    // issue random gathers early (latency hides under ze compute)
    H8 zd[4], zs[4];
#pragma unroll
    for (int s = 0; s < 4; ++s) {
      zd[s].i = *reinterpret_cast<const int4*>(zds + (size_t)dst0 * 256 + s * 32 + g * 8);
      zs[s].i = *reinterpret_cast<const int4*>(zds + (size_t)src0 * 256 + 128 + s * 32 + g * 8);
    }

    // ze = We^T eattr (A rows = 16 edges)
    H8 aE;
    aE.i = make_int4(0, 0, 0, 0);
    if (g < 2) aE.i = *reinterpret_cast<const int4*>(ebfS + (size_t)ii0 * DE + g * 8);
    f32x4 ze[8];
#pragma unroll
    for (int n = 0; n < 8; ++n)
#pragma unroll
      for (int q = 0; q < 4; ++q) ze[n][q] = 0.f;
#pragma unroll
    for (int n = 0; n < 8; ++n) {
      f16x8 b = *reinterpret_cast<const f16x8*>(Wels + (n << 9) + (lane << 3));
      ze[n] = MFMAH(aE.f, b, ze[n]);
    }

    // C-frag (row=edge g*4+j, chan n*16+r) -> [16 rows][136-short rows] LDS
#pragma unroll
    for (int n = 0; n < 8; ++n)
#pragma unroll
      for (int j = 0; j < 4; ++j) {
        int row = g * 4 + j;
        zeb[row * 136 + ((n * 2 + (r >> 3)) << 3) + (r & 7)] = f2h(ze[n][j]);
      }

    f32x4 c[8];
#pragma unroll
    for (int n = 0; n < 8; ++n)
#pragma unroll
      for (int q = 0; q < 4; ++q) c[n][q] = 0.f;

    // GEMM2: A-frag row=r, chans k=s*32+g*8 -> granule s*4+g
#pragma unroll
    for (int s = 0; s < 4; ++s) {
      H8 zeA, m;
      zeA.i = *reinterpret_cast<const int4*>(zeb + r * 136 + ((s * 4 + g) << 3));
#pragma unroll
      for (int w = 0; w < 4; ++w)
        m.u[w] = pk_relu(pk_add(pk_add(zd[s].u[w], zs[s].u[w]), zeA.u[w]));
      __builtin_amdgcn_s_setprio(1);
#pragma unroll
      for (int n = 0; n < 8; ++n) {
        f16x8 b = *reinterpret_cast<const f16x8*>(W2ls + ((s * 8 + n) << 9) + (lane << 3));
        c[n] = MFMAH(m.f, b, c[n]);
      }
      __builtin_amdgcn_s_setprio(0);
    }

    // ---- epilogue: bias+relu, run-compress same-dst rows, atomic scatter (R7-validated) ----
    // lane (g,r) holds c[n][j] for edge t*128 + wid*16 + g*4 + j, chan n*16+r
    int dm[4];
#pragma unroll
    for (int j = 0; j < 4; ++j) dm[j] = __shfl(dst0, g * 4 + j, 64);
#pragma unroll
    for (int n = 0; n < 8; ++n) {
      float run = 0.f; int dcur = -1;
#pragma unroll
      for (int j = 0; j < 4; ++j) {
        int eg = t * 128 + wid * 16 + g * 4 + j;
        float vv = fmaxf(c[n][j] + bia2[n], 0.f);
        if (eg < E) {
          if (dm[j] != dcur) {
            if (dcur >= 0) unsafeAtomicAdd(agg + (size_t)dcur * D + n * 16 + r, run);
            dcur = dm[j]; run = 0.f;
          }
          run += vv;
        }
      }
      if (dcur >= 0) unsafeAtomicAdd(agg + (size_t)dcur * D + n * 16 + r, run);
    }
  }
}

// ---------------- node update + fused next-layer z-GEMM ----------------
// R14: launch_bounds(256,6) -> 6 blocks/CU (VGPR cap 85 >= measured 72).
__global__ __launch_bounds__(256, 6)
void node_kernel(const unsigned short* __restrict__ hbf,
                 const unsigned short* __restrict__ aggbf,
                 const unsigned short* __restrict__ W1f,
                 const unsigned short* __restrict__ W2f,
                 const float* __restrict__ b1,
                 const float* __restrict__ b2,
                 float* __restrict__ h,
                 unsigned short* __restrict__ hbfo,
                 const unsigned short* __restrict__ Wzf,
                 const float* __restrict__ b1n,
                 unsigned short* __restrict__ zds, int N) {
  __shared__ unsigned short m1ls[4][16 * 128];

  const int tid = threadIdx.x, wid = tid >> 6, lane = tid & 63, g = lane >> 4, r = lane & 15;
  const int nbase = blockIdx.x * 64;
  const int nr0 = nbase + wid * 16 + r;
  const int ar0 = (nr0 < N) ? nr0 : (N - 1);

  bf16x8 aH0[4], aG0[4];
#pragma unroll
  for (int s = 0; s < 4; ++s) {
    aH0[s] = *reinterpret_cast<const bf16x8*>(hbf + (size_t)ar0 * D + s * 32 + g * 8);
    aG0[s] = *reinterpret_cast<const bf16x8*>(aggbf + (size_t)ar0 * D + s * 32 + g * 8);
  }

  // hoisted epilogue h-row f32 loads (overlap with U1/U2 MFMA)
  float hv[4][8];
#pragma unroll
  for (int j = 0; j < 4; ++j) {
    int node = nbase + wid * 16 + g * 4 + j;
    int an = (node < N) ? node : (N - 1);
#pragma unroll
    for (int n = 0; n < 8; ++n)
      hv[j][n] = h[(size_t)an * D + n * 16 + r];
  }

  float bia1[8], bia2[8];
#pragma unroll
  for (int n = 0; n < 8; ++n) { bia1[n] = b1[n * 16 + r]; bia2[n] = b2[n * 16 + r]; }

  f32x4 acc0[8];
#pragma unroll
  for (int n = 0; n < 8; ++n)
#pragma unroll
    for (int q = 0; q < 4; ++q) acc0[n][q] = 0.f;

#pragma unroll
  for (int s = 0; s < S_U1; ++s) {
    bf16x8 a0 = (s < 4) ? aH0[s & 3] : aG0[(s - 4) & 3];
#pragma unroll
    for (int n = 0; n < 8; ++n) {
      bf16x8 b = *reinterpret_cast<const bf16x8*>(W1f + (((s * 8 + n) << 9) + (lane << 3)));
      acc0[n] = MFMAB(a0, b, acc0[n]);
    }
  }

  unsigned short* m1w = &m1ls[wid][0];
#pragma unroll
  for (int n = 0; n < 8; ++n)
#pragma unroll
    for (int j = 0; j < 4; ++j) {
      int col = n * 16 + r;
      int row0 = g * 4 + j;
      m1w[row0 * 128 + (col ^ ((row0 & 7) << 3))] = f2bf(fmaxf(acc0[n][j] + bia1[n], 0.f));
    }

  f32x4 c0[8];
#pragma unroll
  for (int n = 0; n < 8; ++n)
#pragma unroll
    for (int q = 0; q < 4; ++q) c0[n][q] = 0.f;

#pragma unroll
  for (int s = 0; s < S_U2; ++s) {
    int k0 = s * 32 + g * 8;
    bf16x8 a0 = *reinterpret_cast<const bf16x8*>(m1w + r * 128 + (k0 ^ ((r & 7) << 3)));
#pragma unroll
    for (int n = 0; n < 8; ++n) {
      bf16x8 b = *reinterpret_cast<const bf16x8*>(W2f + (((s * 8 + n) << 9) + (lane << 3)));
      c0[n] = MFMAB(a0, b, c0[n]);
    }
  }

#pragma unroll
  for (int j = 0; j < 4; ++j) {
    int node = nbase + wid * 16 + g * 4 + j;
    if (node < N) {
#pragma unroll
      for (int n = 0; n < 8; ++n) {
        int col = n * 16 + r;
        float hvnew = hv[j][n] + fmaxf(c0[n][j] + bia2[n], 0.f);
        h[(size_t)node * D + col] = hvnew;
        unsigned short hb = f2bf(hvnew);
        hbfo[(size_t)node * D + col] = hb;
        int row0 = g * 4 + j;
        m1w[row0 * 128 + (col ^ ((row0 & 7) << 3))] = hb;
      }
    }
  }

  if (Wzf != nullptr) {
    bf16x8 aZ[4];
#pragma unroll
    for (int s = 0; s < 4; ++s) {
      int k0 = s * 32 + g * 8;
      aZ[s] = *reinterpret_cast<const bf16x8*>(m1w + r * 128 + (k0 ^ ((r & 7) << 3)));
    }
    float bz[8];
#pragma unroll
    for (int n = 0; n < 8; ++n) bz[n] = b1n[n * 16 + r];
#pragma unroll
    for (int half = 0; half < 2; ++half) {
      f32x4 zacc[8];
#pragma unroll
      for (int n = 0; n < 8; ++n)
#pragma unroll
        for (int q = 0; q < 4; ++q) zacc[n][q] = 0.f;
#pragma unroll
      for (int s = 0; s < 4; ++s)
#pragma unroll
        for (int n = 0; n < 8; ++n)
          zacc[n] = MFMAB(aZ[s], *reinterpret_cast<const bf16x8*>(Wzf + (((s * 16 + half * 8 + n) << 9) + (lane << 3))), zacc[n]);
#pragma unroll
      for (int n = 0; n < 8; ++n)
#pragma unroll
        for (int j = 0; j < 4; ++j) {
          int node = nbase + wid * 16 + g * 4 + j;
          if (node < N) {
            float v = zacc[n][j] + (half == 0 ? bz[n] : 0.f);
            zds[(size_t)node * 256 + (half * 8 + n) * 16 + r] = f2h(v);
          }
        }
    }
  }
}

extern "C" void kernel_launch(void* const* d_in, const int* in_sizes, int n_in,
                              void* d_out, int out_size, void* d_ws, size_t ws_size,
                              hipStream_t stream) {
  const float* x     = (const float*)d_in[0];
  const int*   eidx  = (const int*)d_in[1];
  const float* eattr = (const float*)d_in[2];
  const float* Win   = (const float*)d_in[3];
  const float* bin   = (const float*)d_in[4];
  const float* Wm1 = (const float*)d_in[5];  const float* bm1 = (const float*)d_in[6];
  const float* gm1 = (const float*)d_in[7];  const float* bem1 = (const float*)d_in[8];
  const float* mm1 = (const float*)d_in[9];  const float* vm1 = (const float*)d_in[10];
  const float* Wm2 = (const float*)d_in[11]; const float* bm2 = (const float*)d_in[12];
  const float* gm2 = (const float*)d_in[13]; const float* bem2 = (const float*)d_in[14];
  const float* mm2 = (const float*)d_in[15]; const float* vm2 = (const float*)d_in[16];
  const float* Wu1 = (const float*)d_in[17]; const float* bu1 = (const float*)d_in[18];
  const float* gu1 = (const float*)d_in[19]; const float* beu1 = (const float*)d_in[20];
  const float* mu1 = (const float*)d_in[21]; const float* vu1 = (const float*)d_in[22];
  const float* Wu2 = (const float*)d_in[23]; const float* bu2 = (const float*)d_in[24];
  const float* gu2 = (const float*)d_in[25]; const float* beu2 = (const float*)d_in[26];
  const float* mu2 = (const float*)d_in[27]; const float* vu2 = (const float*)d_in[28];

  const int N = in_sizes[0] / 64;
  const int E = in_sizes[1] / 2;
  float* h = (float*)d_out;

  const int T = (E + 127) / 128;             // msg tiles (128 edges each)

  // workspace layout (16B-aligned slabs), ~110 MB
  char* ws = (char*)d_ws;
  size_t off = 0;
  float* agg = (float*)(ws + off);                     off += (size_t)N * D * 4;
  unsigned short* aggbf = (unsigned short*)(ws + off); off += (size_t)N * D * 2;
  unsigned short* hbf   = (unsigned short*)(ws + off); off += (size_t)N * D * 2;
  unsigned short* zds   = (unsigned short*)(ws + off); off += (size_t)N * 256 * 2;
  unsigned short* xbf   = (unsigned short*)(ws + off); off += (size_t)N * 64 * 2;
  unsigned short* ebfS  = (unsigned short*)(ws + off); off += (size_t)E * DE * 2;
  int* dstS = (int*)(ws + off);                        off += (size_t)E * 4;
  int* srcS = (int*)(ws + off);                        off += (size_t)E * 4;
  int* eidS = (int*)(ws + off);                        off += (size_t)E * 4;
  int* hist = (int*)(ws + off);                        off += ((size_t)N * 4 + 15) & ~15ull;
  int* bsum = (int*)(ws + off);                        off += 1024;
  unsigned short* Wef   = (unsigned short*)(ws + off); off += (size_t)NL * 4096 * 2;
  unsigned short* W2f16 = (unsigned short*)(ws + off); off += (size_t)NL * 16384 * 2;
  unsigned short* Wzf   = (unsigned short*)(ws + off); off += (size_t)NL * 32768 * 2;
  unsigned short* Wu1f  = (unsigned short*)(ws + off); off += (size_t)NL * S_U1 * 4096 * 2;
  unsigned short* Wu2f  = (unsigned short*)(ws + off); off += (size_t)NL * S_U2 * 4096 * 2;
  unsigned short* Wxf   = (unsigned short*)(ws + off); off += (size_t)8192 * 2;
  float* bm1f = (float*)(ws + off); off += (size_t)NL * D * 4;
  float* bm2f = (float*)(ws + off); off += (size_t)NL * D * 4;
  float* bu1f = (float*)(ws + off); off += (size_t)NL * D * 4;
  float* bu2f = (float*)(ws + off); off += (size_t)NL * D * 4;
  if (off > ws_size) return;

  (void)hipFuncSetAttribute(reinterpret_cast<const void*>(msg_kernel),
                            hipFuncAttributeMaxDynamicSharedMemorySize, MSG_LDS);

  // ---- prep: folded frag-ordered weights + biases ----
  {
    int tWe = NL * 4096, tW2 = NL * 16384, tWz = NL * 32768;
    int tU1 = NL * S_U1 * 4096, tU2 = NL * S_U2 * 4096;
    wprep16_kernel<<<(tWe + 255) / 256, 256, 0, stream>>>(Wm1, gm1, vm1, Wef, 272, 256, 16, 1, tWe);
    wprep16_kernel<<<(tW2 + 255) / 256, 256, 0, stream>>>(Wm2, gm2, vm2, W2f16, 128, 0, 128, 4, tW2);
    wprepz_kernel<<<(tWz + 255) / 256, 256, 0, stream>>>(Wm1, gm1, vm1, Wzf, tWz);
    wprep_kernel<<<(tU1 + 255) / 256, 256, 0, stream>>>(Wu1, gu1, vu1, Wu1f, 2 * D, S_U1, tU1);
    wprep_kernel<<<(tU2 + 255) / 256, 256, 0, stream>>>(Wu2, gu2, vu2, Wu2f, D, S_U2, tU2);
    wprepx_kernel<<<32, 256, 0, stream>>>(Win, Wxf);
    cvtx_kernel<<<(N * 8 + 255) / 256, 256, 0, stream>>>(x, xbf, N * 8);
    bprep_kernel<<<2, 256, 0, stream>>>(bm1, gm1, bem1, mm1, vm1, bm1f);
    bprep_kernel<<<2, 256, 0, stream>>>(bm2, gm2, bem2, mm2, vm2, bm2f);
    bprep_kernel<<<2, 256, 0, stream>>>(bu1, gu1, beu1, mu1, vu1, bu1f);
    bprep_kernel<<<2, 256, 0, stream>>>(bu2, gu2, beu2, mu2, vu2, bu2f);
  }

  // ---- counting sort of edges by dst ----
  {
    const int NB_H = (N + 255) / 256;
    (void)hipMemsetAsync(hist, 0, (size_t)N * 4, stream);
    hist_kernel<<<(E + 255) / 256, 256, 0, stream>>>(eidx, hist, E);
    scan1_kernel<<<NB_H, 256, 0, stream>>>(hist, bsum, N);
    scan2_kernel<<<1, 256, 0, stream>>>(bsum, NB_H);
    scan3_kernel<<<NB_H, 256, 0, stream>>>(hist, bsum, N);
    scatter_kernel<<<(E + 255) / 256, 256, 0, stream>>>(eidx, hist, dstS, srcS, eidS, E);
    eperm_kernel<<<(E + 255) / 256, 256, 0, stream>>>(eattr, eidS, ebfS, E);
  }

  // ---- fused input projection + layer-0 z (MFMA) ----
  const int nblocks = (N + 63) / 64;
  xz_kernel<<<nblocks, 256, 0, stream>>>(xbf, Wxf, bin, Wzf, bm1f, h, hbf, zds, N);

  // ---- layers ----
  const int n8 = N * D / 8;
  for (int l = 0; l < NL; ++l) {
    (void)hipMemsetAsync(agg, 0, (size_t)N * D * 4, stream);
    msg_kernel<<<NBMSG, 512, MSG_LDS, stream>>>(zds, ebfS, dstS, srcS,
                                                Wef + (size_t)l * 4096,
                                                W2f16 + (size_t)l * 16384,
                                                bm2f + l * D, agg, E, T);
    agg2bf_kernel<<<(n8 + 255) / 256, 256, 0, stream>>>(agg, aggbf, n8);
    const unsigned short* WzNext = (l < NL - 1) ? (Wzf + (size_t)(l + 1) * 32768) : nullptr;
    const float* b1Next = bm1f + ((l < NL - 1) ? (l + 1) : 0) * D;
    node_kernel<<<nblocks, 256, 0, stream>>>(hbf, aggbf,
                                             Wu1f + (size_t)l * S_U1 * 4096,
                                             Wu2f + (size_t)l * S_U2 * 4096,
                                             bu1f + l * D, bu2f + l * D, h, hbf,
                                             WzNext, b1Next, zds, N);
  }
}

// Round 15
// 848.277 us; speedup vs baseline: 1.3082x; 1.3082x over previous
//
#include <hip/hip_runtime.h>
#include <hip/hip_fp16.h>

#define D 128
#define DE 16
#define NL 4
#define EPSV 1e-5f
#define S_U1 8
#define S_U2 4
#define NBMSG 512      // msg persistent blocks (2/CU, LDS-limited)
#define MSG_LDS 75776  // 8K We + 32K W2 + 8*4352 zeb

using f32x4  = __attribute__((ext_vector_type(4))) float;
using bf16x8 = __attribute__((ext_vector_type(8))) short;
typedef _Float16 f16x8 __attribute__((ext_vector_type(8)));

#define MFMAB(a, b, c) __builtin_amdgcn_mfma_f32_16x16x32_bf16((a), (b), (c), 0, 0, 0)
#define MFMAH(a, b, c) __builtin_amdgcn_mfma_f32_16x16x32_f16((a), (b), (c), 0, 0, 0)

union H8 { int4 i; unsigned int u[4]; f16x8 f; };

__device__ __forceinline__ unsigned short f2bf(float x) {
  unsigned int u = __float_as_uint(x);
  u = (u + 0x7FFFu + ((u >> 16) & 1u)) >> 16;  // RNE
  return (unsigned short)u;
}

__device__ __forceinline__ unsigned short f2h(float x) {
  return __half_as_ushort(__float2half(x));
}

__device__ __forceinline__ float h2f(unsigned short x) {
  return __half2float(__ushort_as_half(x));
}

// packed f16 math via VOP3P inline asm (validated R9-R13)
__device__ __forceinline__ unsigned int pk_add(unsigned int a, unsigned int b) {
  unsigned int r;
  asm("v_pk_add_f16 %0, %1, %2" : "=v"(r) : "v"(a), "v"(b));
  return r;
}
__device__ __forceinline__ unsigned int pk_relu(unsigned int a) {
  unsigned int r;
  asm("v_pk_max_f16 %0, %1, 0" : "=v"(r) : "v"(a));
  return r;
}

// CONTRACT (m104/m108): LDS dest = wave-uniform base + lane*16. Call sites MUST
// use idx = i*blockDim + tid so consecutive lanes write consecutive granules.
__device__ __forceinline__ void gload_lds16(const void* gp, void* lp) {
  typedef __attribute__((address_space(1))) unsigned int as1_u32;
  typedef __attribute__((address_space(3))) unsigned int as3_u32;
  __builtin_amdgcn_global_load_lds((as1_u32*)(unsigned long long)gp,
                                   (as3_u32*)(unsigned int)(unsigned long long)lp,
                                   16, 0, 0);
}

__device__ __forceinline__ bf16x8 pack8(float4 a, float4 b) {
  bf16x8 o;
  o[0] = (short)f2bf(a.x); o[1] = (short)f2bf(a.y);
  o[2] = (short)f2bf(a.z); o[3] = (short)f2bf(a.w);
  o[4] = (short)f2bf(b.x); o[5] = (short)f2bf(b.y);
  o[6] = (short)f2bf(b.z); o[7] = (short)f2bf(b.w);
  return o;
}

__device__ __forceinline__ int4 pack8h(float4 a, float4 b) {
  int4 o;
  o.x = (int)((unsigned)f2h(a.x) | ((unsigned)f2h(a.y) << 16));
  o.y = (int)((unsigned)f2h(a.z) | ((unsigned)f2h(a.w) << 16));
  o.z = (int)((unsigned)f2h(b.x) | ((unsigned)f2h(b.y) << 16));
  o.w = (int)((unsigned)f2h(b.z) | ((unsigned)f2h(b.w) << 16));
  return o;
}

// ---------------- prep kernels (validated) ----------------
__global__ void wprep_kernel(const float* __restrict__ W, const float* __restrict__ g,
                             const float* __restrict__ v, unsigned short* __restrict__ out,
                             int K, int S, int total) {
  int idx = blockIdx.x * 256 + threadIdx.x;
  if (idx >= total) return;
  int e = idx & 7, l0 = (idx >> 3) & 63, f = idx >> 9;
  int n = f & 7, sf = f >> 3, s = sf % S, l = sf / S;
  int k = s * 32 + ((l0 >> 4) << 3) + e;
  int c = (n << 4) + (l0 & 15);
  float val = 0.f;
  if (k < K) {
    float sc = g[l * D + c] * rsqrtf(v[l * D + c] + EPSV);
    val = W[((size_t)(l * K + k)) * D + c] * sc;
  }
  out[idx] = f2bf(val);
}

__global__ void wprep16_kernel(const float* __restrict__ W, const float* __restrict__ g,
                               const float* __restrict__ v, unsigned short* __restrict__ out,
                               int Ktot, int ko, int Kact, int S, int total) {
  int idx = blockIdx.x * 256 + threadIdx.x;
  if (idx >= total) return;
  int e = idx & 7, l0 = (idx >> 3) & 63, f = idx >> 9;
  int n = f & 7, sf = f >> 3, s = sf % S, l = sf / S;
  int k = s * 32 + ((l0 >> 4) << 3) + e;
  int c = (n << 4) + (l0 & 15);
  float val = 0.f;
  if (k < Kact) {
    float sc = g[l * D + c] * rsqrtf(v[l * D + c] + EPSV);
    val = W[((size_t)(l * Ktot + ko + k)) * D + c] * sc;
  }
  out[idx] = f2h(val);
}

__global__ void wprepz_kernel(const float* __restrict__ W1, const float* __restrict__ g,
                              const float* __restrict__ v, unsigned short* __restrict__ out,
                              int total) {
  int idx = blockIdx.x * 256 + threadIdx.x;
  if (idx >= total) return;
  int e = idx & 7, l0 = (idx >> 3) & 63, f = idx >> 9;
  int n = f & 15, sf = f >> 4, s = sf & 3, l = sf >> 2;
  int k = s * 32 + ((l0 >> 4) << 3) + e;
  int c = ((n & 7) << 4) + (l0 & 15);
  int row = (n < 8) ? k : 128 + k;
  float sc = g[l * D + c] * rsqrtf(v[l * D + c] + EPSV);
  float val = W1[((size_t)(l * 272 + row)) * D + c] * sc;
  out[idx] = f2bf(val);
}

// Win frag-order, K=64 (S=2), no BN fold
__global__ void wprepx_kernel(const float* __restrict__ Win, unsigned short* __restrict__ out) {
  int idx = blockIdx.x * 256 + threadIdx.x;
  if (idx >= 8192) return;
  int e = idx & 7, l0 = (idx >> 3) & 63, f = idx >> 9;
  int n = f & 7, s = f >> 3;
  int k = s * 32 + ((l0 >> 4) << 3) + e;
  int c = (n << 4) + (l0 & 15);
  out[idx] = f2bf(Win[k * D + c]);
}

__global__ void cvtx_kernel(const float* __restrict__ x, unsigned short* __restrict__ xbf, int n8) {
  int idx = blockIdx.x * 256 + threadIdx.x;
  if (idx >= n8) return;
  float4 a = reinterpret_cast<const float4*>(x)[idx * 2];
  float4 b = reinterpret_cast<const float4*>(x)[idx * 2 + 1];
  reinterpret_cast<bf16x8*>(xbf)[idx] = pack8(a, b);
}

__global__ void bprep_kernel(const float* __restrict__ b, const float* __restrict__ g,
                             const float* __restrict__ be, const float* __restrict__ m,
                             const float* __restrict__ v, float* __restrict__ out) {
  int idx = blockIdx.x * 256 + threadIdx.x;
  if (idx >= NL * D) return;
  float s = g[idx] * rsqrtf(v[idx] + EPSV);
  out[idx] = (b[idx] - m[idx]) * s + be[idx];
}

// ---------------- fused xproj + layer-0 z-GEMM (validated R12/R13) ----------------
__global__ __launch_bounds__(256)
void xz_kernel(const unsigned short* __restrict__ xbf,
               const unsigned short* __restrict__ Wxf,
               const float* __restrict__ bin,
               const unsigned short* __restrict__ Wzf,
               const float* __restrict__ b1,
               float* __restrict__ h,
               unsigned short* __restrict__ hbf,
               unsigned short* __restrict__ zds, int N) {
  __shared__ unsigned short m1ls[4][16 * 128];
  const int tid = threadIdx.x, wid = tid >> 6, lane = tid & 63, g = lane >> 4, r = lane & 15;
  const int nbase = blockIdx.x * 64;
  const int nr = nbase + wid * 16 + r;
  const int ar = (nr < N) ? nr : (N - 1);

  bf16x8 aX[2];
#pragma unroll
  for (int s = 0; s < 2; ++s)
    aX[s] = *reinterpret_cast<const bf16x8*>(xbf + (size_t)ar * 64 + s * 32 + g * 8);

  f32x4 acc[8];
#pragma unroll
  for (int n = 0; n < 8; ++n)
#pragma unroll
    for (int q = 0; q < 4; ++q) acc[n][q] = 0.f;
#pragma unroll
  for (int s = 0; s < 2; ++s)
#pragma unroll
    for (int n = 0; n < 8; ++n)
      acc[n] = MFMAB(aX[s], *reinterpret_cast<const bf16x8*>(Wxf + (((s * 8 + n) << 9) + (lane << 3))), acc[n]);

  float bia[8];
#pragma unroll
  for (int n = 0; n < 8; ++n) bia[n] = bin[n * 16 + r];

  unsigned short* m1w = &m1ls[wid][0];
#pragma unroll
  for (int j = 0; j < 4; ++j) {
    int node = nbase + wid * 16 + g * 4 + j;
    if (node < N) {
#pragma unroll
      for (int n = 0; n < 8; ++n) {
        int col = n * 16 + r;
        float hv = acc[n][j] + bia[n];
        h[(size_t)node * D + col] = hv;
        unsigned short hb = f2bf(hv);
        hbf[(size_t)node * D + col] = hb;
        int row0 = g * 4 + j;
        m1w[row0 * 128 + (col ^ ((row0 & 7) << 3))] = hb;
      }
    }
  }

  bf16x8 aZ[4];
#pragma unroll
  for (int s = 0; s < 4; ++s) {
    int k0 = s * 32 + g * 8;
    aZ[s] = *reinterpret_cast<const bf16x8*>(m1w + r * 128 + (k0 ^ ((r & 7) << 3)));
  }
  float bz[8];
#pragma unroll
  for (int n = 0; n < 8; ++n) bz[n] = b1[n * 16 + r];
#pragma unroll
  for (int half = 0; half < 2; ++half) {
    f32x4 zacc[8];
#pragma unroll
    for (int n = 0; n < 8; ++n)
#pragma unroll
      for (int q = 0; q < 4; ++q) zacc[n][q] = 0.f;
#pragma unroll
    for (int s = 0; s < 4; ++s)
#pragma unroll
      for (int n = 0; n < 8; ++n)
        zacc[n] = MFMAB(aZ[s], *reinterpret_cast<const bf16x8*>(Wzf + (((s * 16 + half * 8 + n) << 9) + (lane << 3))), zacc[n]);
#pragma unroll
    for (int n = 0; n < 8; ++n)
#pragma unroll
      for (int j = 0; j < 4; ++j) {
        int node = nbase + wid * 16 + g * 4 + j;
        if (node < N) {
          float v = zacc[n][j] + (half == 0 ? bz[n] : 0.f);
          zds[(size_t)node * 256 + (half * 8 + n) * 16 + r] = f2h(v);
        }
      }
  }
}

// ---------------- counting sort of edges by dst (validated) ----------------
__global__ void hist_kernel(const int* __restrict__ eidx, int* __restrict__ hist, int E) {
  int e = blockIdx.x * 256 + threadIdx.x;
  if (e < E) atomicAdd(&hist[eidx[E + e]], 1);
}

__global__ void scan1_kernel(const int* __restrict__ hist, int* __restrict__ bsum, int N) {
  __shared__ int sb[256];
  int i = blockIdx.x * 256 + threadIdx.x;
  sb[threadIdx.x] = (i < N) ? hist[i] : 0;
  __syncthreads();
  for (int d = 128; d > 0; d >>= 1) {
    if (threadIdx.x < d) sb[threadIdx.x] += sb[threadIdx.x + d];
    __syncthreads();
  }
  if (threadIdx.x == 0) bsum[blockIdx.x] = sb[0];
}

__global__ void scan2_kernel(int* __restrict__ bsum, int nb) {
  __shared__ int sb[2][256];
  int t = threadIdx.x;
  int v = (t < nb) ? bsum[t] : 0;
  int p = 0;
  sb[0][t] = v; __syncthreads();
#pragma unroll
  for (int d = 1; d < 256; d <<= 1) {
    int nv = sb[p][t] + ((t >= d) ? sb[p][t - d] : 0);
    sb[p ^ 1][t] = nv; p ^= 1;
    __syncthreads();
  }
  if (t < nb) bsum[t] = sb[p][t] - v;
}

__global__ void scan3_kernel(int* __restrict__ hist, const int* __restrict__ bsum, int N) {
  __shared__ int sb[2][256];
  int i = blockIdx.x * 256 + threadIdx.x, t = threadIdx.x;
  int v = (i < N) ? hist[i] : 0;
  int p = 0;
  sb[0][t] = v; __syncthreads();
#pragma unroll
  for (int d = 1; d < 256; d <<= 1) {
    int nv = sb[p][t] + ((t >= d) ? sb[p][t - d] : 0);
    sb[p ^ 1][t] = nv; p ^= 1;
    __syncthreads();
  }
  if (i < N) hist[i] = sb[p][t] - v + bsum[blockIdx.x];
}

__global__ void scatter_kernel(const int* __restrict__ eidx, int* __restrict__ cursor,
                               int* __restrict__ dstS, int* __restrict__ srcS,
                               int* __restrict__ eidS, int E) {
  int e = blockIdx.x * 256 + threadIdx.x;
  if (e >= E) return;
  int d = eidx[E + e];
  int pos = atomicAdd(&cursor[d], 1);
  dstS[pos] = d;
  srcS[pos] = eidx[e];
  eidS[pos] = e;
}
// NOTE: after scatter, cursor[v] == END offset of segment v (CSR).

__global__ void eperm_kernel(const float* __restrict__ eattr, const int* __restrict__ eidS,
                             unsigned short* __restrict__ ebfS, int E) {
  int i = blockIdx.x * 256 + threadIdx.x;
  if (i >= E) return;
  const float4* src = reinterpret_cast<const float4*>(eattr + (size_t)eidS[i] * DE);
  *reinterpret_cast<int4*>(ebfS + (size_t)i * DE) = pack8h(src[0], src[1]);
  *reinterpret_cast<int4*>(ebfS + (size_t)i * DE + 8) = pack8h(src[2], src[3]);
}

// ---------------- fused message kernel (R13 two-phase, + next-tile index prefetch) ----------------
__global__ __launch_bounds__(512, 4)
void msg_kernel(const unsigned short* __restrict__ zds,
                const unsigned short* __restrict__ ebfS,
                const int* __restrict__ dstS,
                const int* __restrict__ srcS,
                const unsigned short* __restrict__ Wef,   // f16 frag, 8KB
                const unsigned short* __restrict__ W2f,   // f16 frag, 32KB
                const float* __restrict__ b2,
                unsigned short* __restrict__ msgb, int E, int T) {
  extern __shared__ char smem[];
  unsigned short* Wels = (unsigned short*)smem;            // We: [0, 4096) shorts
  unsigned short* W2ls = (unsigned short*)(smem + 8192);   // W2: 16384 shorts
  const int tid = threadIdx.x;
  const int wid = tid >> 6, lane = tid & 63, g = lane >> 4, r = lane & 15;
  unsigned short* zeb = (unsigned short*)(smem + 40960 + wid * 4352);  // 16x136 shorts/wave

  gload_lds16(Wef + ((size_t)tid << 3), smem + (tid << 4));
#pragma unroll
  for (int i = 0; i < 4; ++i) {
    int idx = i * 512 + tid;
    gload_lds16(W2f + ((size_t)idx << 3), smem + 8192 + (idx << 4));
  }

  float bia2[8];
#pragma unroll
  for (int n = 0; n < 8; ++n) bia2[n] = b2[n * 16 + r];

  const int t0 = (int)(((long long)blockIdx.x * T) / gridDim.x);
  const int t1 = (int)(((long long)(blockIdx.x + 1) * T) / gridDim.x);

  __syncthreads();

  // prefetch first tile's indices (removes index-load from the per-tile chain)
  int ii_n = 0, dst_n = 0, src_n = 0;
  if (t0 < t1) {
    ii_n = min(t0 * 128 + wid * 16 + r, E - 1);
    dst_n = dstS[ii_n]; src_n = srcS[ii_n];
  }

  for (int t = t0; t < t1; ++t) {
    const int ii0 = ii_n;
    const int dst0 = dst_n, src0 = src_n;

    // issue random gathers for current tile immediately
    H8 zd[4], zs[4];
#pragma unroll
    for (int s = 0; s < 4; ++s) {
      zd[s].i = *reinterpret_cast<const int4*>(zds + (size_t)dst0 * 256 + s * 32 + g * 8);
      zs[s].i = *reinterpret_cast<const int4*>(zds + (size_t)src0 * 256 + 128 + s * 32 + g * 8);
    }

    // prefetch next tile's indices (latency hidden under this tile's compute)
    if (t + 1 < t1) {
      ii_n = min((t + 1) * 128 + wid * 16 + r, E - 1);
      dst_n = dstS[ii_n]; src_n = srcS[ii_n];
    }

    // ze = We^T eattr (A rows = 16 edges)
    H8 aE;
    aE.i = make_int4(0, 0, 0, 0);
    if (g < 2) aE.i = *reinterpret_cast<const int4*>(ebfS + (size_t)ii0 * DE + g * 8);
    f32x4 ze[8];
#pragma unroll
    for (int n = 0; n < 8; ++n)
#pragma unroll
      for (int q = 0; q < 4; ++q) ze[n][q] = 0.f;
#pragma unroll
    for (int n = 0; n < 8; ++n) {
      f16x8 b = *reinterpret_cast<const f16x8*>(Wels + (n << 9) + (lane << 3));
      ze[n] = MFMAH(aE.f, b, ze[n]);
    }

    // C-frag (row=edge g*4+j, chan n*16+r) -> [16 rows][136-short rows] LDS
#pragma unroll
    for (int n = 0; n < 8; ++n)
#pragma unroll
      for (int j = 0; j < 4; ++j) {
        int row = g * 4 + j;
        zeb[row * 136 + ((n * 2 + (r >> 3)) << 3) + (r & 7)] = f2h(ze[n][j]);
      }

    f32x4 c[8];
#pragma unroll
    for (int n = 0; n < 8; ++n)
#pragma unroll
      for (int q = 0; q < 4; ++q) c[n][q] = 0.f;

    // GEMM2: A-frag row=r, chans k=s*32+g*8 -> granule s*4+g
#pragma unroll
    for (int s = 0; s < 4; ++s) {
      H8 zeA, m;
      zeA.i = *reinterpret_cast<const int4*>(zeb + r * 136 + ((s * 4 + g) << 3));
#pragma unroll
      for (int w = 0; w < 4; ++w)
        m.u[w] = pk_relu(pk_add(pk_add(zd[s].u[w], zs[s].u[w]), zeA.u[w]));
      __builtin_amdgcn_s_setprio(1);
#pragma unroll
      for (int n = 0; n < 8; ++n) {
        f16x8 b = *reinterpret_cast<const f16x8*>(W2ls + ((s * 8 + n) << 9) + (lane << 3));
        c[n] = MFMAH(m.f, b, c[n]);
      }
      __builtin_amdgcn_s_setprio(0);
    }

    // epilogue: bias+relu -> f16 quad store; q = t*32 + wid*4 + g
#pragma unroll
    for (int n = 0; n < 8; ++n) {
      unsigned int lo = (unsigned)f2h(fmaxf(c[n][0] + bia2[n], 0.f))
                      | ((unsigned)f2h(fmaxf(c[n][1] + bia2[n], 0.f)) << 16);
      unsigned int hi = (unsigned)f2h(fmaxf(c[n][2] + bia2[n], 0.f))
                      | ((unsigned)f2h(fmaxf(c[n][3] + bia2[n], 0.f)) << 16);
      size_t addr8 = ((((size_t)t * 32 + wid * 4 + g) * 8 + n) * 16) + r;
      uint2 pk; pk.x = lo; pk.y = hi;
      *reinterpret_cast<uint2*>(msgb + addr8 * 4) = pk;
    }
  }
}

// ---------------- CSR segment reduce (validated R12/R13) ----------------
__global__ __launch_bounds__(256)
void reduce_kernel(const unsigned short* __restrict__ msgb,
                   const int* __restrict__ csr_end,
                   unsigned short* __restrict__ aggbf, int N) {
  const int tid = threadIdx.x, wid = tid >> 6, lane = tid & 63;
  const int er = lane >> 4, cg = lane & 15;
  for (int v = blockIdx.x * 4 + wid; v < N; v += gridDim.x * 4) {
    const int s = (v == 0) ? 0 : csr_end[v - 1];
    const int e = csr_end[v];
    float a[8];
#pragma unroll
    for (int n = 0; n < 8; ++n) a[n] = 0.f;
    const int qe = (e + 3) >> 2;
    for (int qb = (s >> 2); qb < qe; qb += 4) {
      int q = qb + er;
      if (q < qe) {
        size_t base8 = (size_t)q * 128 + cg;
        int p0 = 4 * q;
#pragma unroll
        for (int n = 0; n < 8; ++n) {
          uint2 d = *reinterpret_cast<const uint2*>(msgb + (base8 + (size_t)n * 16) * 4);
          float v0 = h2f((unsigned short)(d.x & 0xffff));
          float v1 = h2f((unsigned short)(d.x >> 16));
          float v2 = h2f((unsigned short)(d.y & 0xffff));
          float v3 = h2f((unsigned short)(d.y >> 16));
          a[n] += ((p0 >= s && p0 < e) ? v0 : 0.f)
                + ((p0 + 1 >= s && p0 + 1 < e) ? v1 : 0.f)
                + ((p0 + 2 >= s && p0 + 2 < e) ? v2 : 0.f)
                + ((p0 + 3 >= s && p0 + 3 < e) ? v3 : 0.f);
        }
      }
    }
#pragma unroll
    for (int n = 0; n < 8; ++n) {
      a[n] += __shfl_xor(a[n], 16);
      a[n] += __shfl_xor(a[n], 32);
    }
    if (er == 0) {
#pragma unroll
      for (int n = 0; n < 8; ++n)
        aggbf[(size_t)v * 128 + n * 16 + cg] = f2bf(a[n]);
    }
  }
}

// ---------------- node update + fused next-layer z-GEMM ----------------
// R15: launch_bounds(256,6) -> 6 blocks/CU (VGPR cap 85 >= measured 72, no spill).
__global__ __launch_bounds__(256, 6)
void node_kernel(const unsigned short* __restrict__ hbf,
                 const unsigned short* __restrict__ aggbf,
                 const unsigned short* __restrict__ W1f,
                 const unsigned short* __restrict__ W2f,
                 const float* __restrict__ b1,
                 const float* __restrict__ b2,
                 float* __restrict__ h,
                 unsigned short* __restrict__ hbfo,
                 const unsigned short* __restrict__ Wzf,
                 const float* __restrict__ b1n,
                 unsigned short* __restrict__ zds, int N) {
  __shared__ unsigned short m1ls[4][16 * 128];

  const int tid = threadIdx.x, wid = tid >> 6, lane = tid & 63, g = lane >> 4, r = lane & 15;
  const int nbase = blockIdx.x * 64;
  const int nr0 = nbase + wid * 16 + r;
  const int ar0 = (nr0 < N) ? nr0 : (N - 1);

  bf16x8 aH0[4], aG0[4];
#pragma unroll
  for (int s = 0; s < 4; ++s) {
    aH0[s] = *reinterpret_cast<const bf16x8*>(hbf + (size_t)ar0 * D + s * 32 + g * 8);
    aG0[s] = *reinterpret_cast<const bf16x8*>(aggbf + (size_t)ar0 * D + s * 32 + g * 8);
  }

  // hoisted epilogue h-row f32 loads (overlap with U1/U2 MFMA)
  float hv[4][8];
#pragma unroll
  for (int j = 0; j < 4; ++j) {
    int node = nbase + wid * 16 + g * 4 + j;
    int an = (node < N) ? node : (N - 1);
#pragma unroll
    for (int n = 0; n < 8; ++n)
      hv[j][n] = h[(size_t)an * D + n * 16 + r];
  }

  float bia1[8], bia2[8];
#pragma unroll
  for (int n = 0; n < 8; ++n) { bia1[n] = b1[n * 16 + r]; bia2[n] = b2[n * 16 + r]; }

  f32x4 acc0[8];
#pragma unroll
  for (int n = 0; n < 8; ++n)
#pragma unroll
    for (int q = 0; q < 4; ++q) acc0[n][q] = 0.f;

#pragma unroll
  for (int s = 0; s < S_U1; ++s) {
    bf16x8 a0 = (s < 4) ? aH0[s & 3] : aG0[(s - 4) & 3];
#pragma unroll
    for (int n = 0; n < 8; ++n) {
      bf16x8 b = *reinterpret_cast<const bf16x8*>(W1f + (((s * 8 + n) << 9) + (lane << 3)));
      acc0[n] = MFMAB(a0, b, acc0[n]);
    }
  }

  unsigned short* m1w = &m1ls[wid][0];
#pragma unroll
  for (int n = 0; n < 8; ++n)
#pragma unroll
    for (int j = 0; j < 4; ++j) {
      int col = n * 16 + r;
      int row0 = g * 4 + j;
      m1w[row0 * 128 + (col ^ ((row0 & 7) << 3))] = f2bf(fmaxf(acc0[n][j] + bia1[n], 0.f));
    }

  f32x4 c0[8];
#pragma unroll
  for (int n = 0; n < 8; ++n)
#pragma unroll
    for (int q = 0; q < 4; ++q) c0[n][q] = 0.f;

#pragma unroll
  for (int s = 0; s < S_U2; ++s) {
    int k0 = s * 32 + g * 8;
    bf16x8 a0 = *reinterpret_cast<const bf16x8*>(m1w + r * 128 + (k0 ^ ((r & 7) << 3)));
#pragma unroll
    for (int n = 0; n < 8; ++n) {
      bf16x8 b = *reinterpret_cast<const bf16x8*>(W2f + (((s * 8 + n) << 9) + (lane << 3)));
      c0[n] = MFMAB(a0, b, c0[n]);
    }
  }

#pragma unroll
  for (int j = 0; j < 4; ++j) {
    int node = nbase + wid * 16 + g * 4 + j;
    if (node < N) {
#pragma unroll
      for (int n = 0; n < 8; ++n) {
        int col = n * 16 + r;
        float hvnew = hv[j][n] + fmaxf(c0[n][j] + bia2[n], 0.f);
        h[(size_t)node * D + col] = hvnew;
        unsigned short hb = f2bf(hvnew);
        hbfo[(size_t)node * D + col] = hb;
        int row0 = g * 4 + j;
        m1w[row0 * 128 + (col ^ ((row0 & 7) << 3))] = hb;
      }
    }
  }

  if (Wzf != nullptr) {
    bf16x8 aZ[4];
#pragma unroll
    for (int s = 0; s < 4; ++s) {
      int k0 = s * 32 + g * 8;
      aZ[s] = *reinterpret_cast<const bf16x8*>(m1w + r * 128 + (k0 ^ ((r & 7) << 3)));
    }
    float bz[8];
#pragma unroll
    for (int n = 0; n < 8; ++n) bz[n] = b1n[n * 16 + r];
#pragma unroll
    for (int half = 0; half < 2; ++half) {
      f32x4 zacc[8];
#pragma unroll
      for (int n = 0; n < 8; ++n)
#pragma unroll
        for (int q = 0; q < 4; ++q) zacc[n][q] = 0.f;
#pragma unroll
      for (int s = 0; s < 4; ++s)
#pragma unroll
        for (int n = 0; n < 8; ++n)
          zacc[n] = MFMAB(aZ[s], *reinterpret_cast<const bf16x8*>(Wzf + (((s * 16 + half * 8 + n) << 9) + (lane << 3))), zacc[n]);
#pragma unroll
      for (int n = 0; n < 8; ++n)
#pragma unroll
        for (int j = 0; j < 4; ++j) {
          int node = nbase + wid * 16 + g * 4 + j;
          if (node < N) {
            float v = zacc[n][j] + (half == 0 ? bz[n] : 0.f);
            zds[(size_t)node * 256 + (half * 8 + n) * 16 + r] = f2h(v);
          }
        }
    }
  }
}

extern "C" void kernel_launch(void* const* d_in, const int* in_sizes, int n_in,
                              void* d_out, int out_size, void* d_ws, size_t ws_size,
                              hipStream_t stream) {
  const float* x     = (const float*)d_in[0];
  const int*   eidx  = (const int*)d_in[1];
  const float* eattr = (const float*)d_in[2];
  const float* Win   = (const float*)d_in[3];
  const float* bin   = (const float*)d_in[4];
  const float* Wm1 = (const float*)d_in[5];  const float* bm1 = (const float*)d_in[6];
  const float* gm1 = (const float*)d_in[7];  const float* bem1 = (const float*)d_in[8];
  const float* mm1 = (const float*)d_in[9];  const float* vm1 = (const float*)d_in[10];
  const float* Wm2 = (const float*)d_in[11]; const float* bm2 = (const float*)d_in[12];
  const float* gm2 = (const float*)d_in[13]; const float* bem2 = (const float*)d_in[14];
  const float* mm2 = (const float*)d_in[15]; const float* vm2 = (const float*)d_in[16];
  const float* Wu1 = (const float*)d_in[17]; const float* bu1 = (const float*)d_in[18];
  const float* gu1 = (const float*)d_in[19]; const float* beu1 = (const float*)d_in[20];
  const float* mu1 = (const float*)d_in[21]; const float* vu1 = (const float*)d_in[22];
  const float* Wu2 = (const float*)d_in[23]; const float* bu2 = (const float*)d_in[24];
  const float* gu2 = (const float*)d_in[25]; const float* beu2 = (const float*)d_in[26];
  const float* mu2 = (const float*)d_in[27]; const float* vu2 = (const float*)d_in[28];

  const int N = in_sizes[0] / 64;
  const int E = in_sizes[1] / 2;
  float* h = (float*)d_out;

  const int T = (E + 127) / 128;             // msg tiles (128 edges each)
  const size_t Epad = (size_t)T * 128;       // msgb rows

  // workspace layout (16B-aligned slabs), ~210 MB
  char* ws = (char*)d_ws;
  size_t off = 0;
  unsigned short* aggbf = (unsigned short*)(ws + off); off += (size_t)N * D * 2;
  unsigned short* hbf   = (unsigned short*)(ws + off); off += (size_t)N * D * 2;
  unsigned short* zds   = (unsigned short*)(ws + off); off += (size_t)N * 256 * 2;
  unsigned short* xbf   = (unsigned short*)(ws + off); off += (size_t)N * 64 * 2;
  unsigned short* ebfS  = (unsigned short*)(ws + off); off += (size_t)E * DE * 2;
  int* dstS = (int*)(ws + off);                        off += (size_t)E * 4;
  int* srcS = (int*)(ws + off);                        off += (size_t)E * 4;
  int* eidS = (int*)(ws + off);                        off += (size_t)E * 4;
  int* hist = (int*)(ws + off);                        off += ((size_t)N * 4 + 15) & ~15ull;
  int* bsum = (int*)(ws + off);                        off += 1024;
  unsigned short* Wef   = (unsigned short*)(ws + off); off += (size_t)NL * 4096 * 2;
  unsigned short* W2f16 = (unsigned short*)(ws + off); off += (size_t)NL * 16384 * 2;
  unsigned short* Wzf   = (unsigned short*)(ws + off); off += (size_t)NL * 32768 * 2;
  unsigned short* Wu1f  = (unsigned short*)(ws + off); off += (size_t)NL * S_U1 * 4096 * 2;
  unsigned short* Wu2f  = (unsigned short*)(ws + off); off += (size_t)NL * S_U2 * 4096 * 2;
  unsigned short* Wxf   = (unsigned short*)(ws + off); off += (size_t)8192 * 2;
  float* bm1f = (float*)(ws + off); off += (size_t)NL * D * 4;
  float* bm2f = (float*)(ws + off); off += (size_t)NL * D * 4;
  float* bu1f = (float*)(ws + off); off += (size_t)NL * D * 4;
  float* bu2f = (float*)(ws + off); off += (size_t)NL * D * 4;
  unsigned short* msgb = (unsigned short*)(ws + off);  off += Epad * 128 * 2;  // 128 MB m2
  if (off > ws_size) return;

  (void)hipFuncSetAttribute(reinterpret_cast<const void*>(msg_kernel),
                            hipFuncAttributeMaxDynamicSharedMemorySize, MSG_LDS);

  // ---- prep: folded frag-ordered weights + biases ----
  {
    int tWe = NL * 4096, tW2 = NL * 16384, tWz = NL * 32768;
    int tU1 = NL * S_U1 * 4096, tU2 = NL * S_U2 * 4096;
    wprep16_kernel<<<(tWe + 255) / 256, 256, 0, stream>>>(Wm1, gm1, vm1, Wef, 272, 256, 16, 1, tWe);
    wprep16_kernel<<<(tW2 + 255) / 256, 256, 0, stream>>>(Wm2, gm2, vm2, W2f16, 128, 0, 128, 4, tW2);
    wprepz_kernel<<<(tWz + 255) / 256, 256, 0, stream>>>(Wm1, gm1, vm1, Wzf, tWz);
    wprep_kernel<<<(tU1 + 255) / 256, 256, 0, stream>>>(Wu1, gu1, vu1, Wu1f, 2 * D, S_U1, tU1);
    wprep_kernel<<<(tU2 + 255) / 256, 256, 0, stream>>>(Wu2, gu2, vu2, Wu2f, D, S_U2, tU2);
    wprepx_kernel<<<32, 256, 0, stream>>>(Win, Wxf);
    cvtx_kernel<<<(N * 8 + 255) / 256, 256, 0, stream>>>(x, xbf, N * 8);
    bprep_kernel<<<2, 256, 0, stream>>>(bm1, gm1, bem1, mm1, vm1, bm1f);
    bprep_kernel<<<2, 256, 0, stream>>>(bm2, gm2, bem2, mm2, vm2, bm2f);
    bprep_kernel<<<2, 256, 0, stream>>>(bu1, gu1, beu1, mu1, vu1, bu1f);
    bprep_kernel<<<2, 256, 0, stream>>>(bu2, gu2, beu2, mu2, vu2, bu2f);
  }

  // ---- counting sort of edges by dst (hist becomes CSR end offsets) ----
  {
    const int NB_H = (N + 255) / 256;
    (void)hipMemsetAsync(hist, 0, (size_t)N * 4, stream);
    hist_kernel<<<(E + 255) / 256, 256, 0, stream>>>(eidx, hist, E);
    scan1_kernel<<<NB_H, 256, 0, stream>>>(hist, bsum, N);
    scan2_kernel<<<1, 256, 0, stream>>>(bsum, NB_H);
    scan3_kernel<<<NB_H, 256, 0, stream>>>(hist, bsum, N);
    scatter_kernel<<<(E + 255) / 256, 256, 0, stream>>>(eidx, hist, dstS, srcS, eidS, E);
    eperm_kernel<<<(E + 255) / 256, 256, 0, stream>>>(eattr, eidS, ebfS, E);
  }

  // ---- fused input projection + layer-0 z (MFMA) ----
  const int nblocks = (N + 63) / 64;
  xz_kernel<<<nblocks, 256, 0, stream>>>(xbf, Wxf, bin, Wzf, bm1f, h, hbf, zds, N);

  // ---- layers ----
  for (int l = 0; l < NL; ++l) {
    msg_kernel<<<NBMSG, 512, MSG_LDS, stream>>>(zds, ebfS, dstS, srcS,
                                                Wef + (size_t)l * 4096,
                                                W2f16 + (size_t)l * 16384,
                                                bm2f + l * D, msgb, E, T);
    reduce_kernel<<<2048, 256, 0, stream>>>(msgb, hist, aggbf, N);
    const unsigned short* WzNext = (l < NL - 1) ? (Wzf + (size_t)(l + 1) * 32768) : nullptr;
    const float* b1Next = bm1f + ((l < NL - 1) ? (l + 1) : 0) * D;
    node_kernel<<<nblocks, 256, 0, stream>>>(hbf, aggbf,
                                             Wu1f + (size_t)l * S_U1 * 4096,
                                             Wu2f + (size_t)l * S_U2 * 4096,
                                             bu1f + l * D, bu2f + l * D, h, hbf,
                                             WzNext, b1Next, zds, N);
  }
}

// Round 16
// 568.151 us; speedup vs baseline: 1.9532x; 1.4930x over previous
//
#include <hip/hip_runtime.h>
#include <hip/hip_fp16.h>

#define D 128
#define DE 16
#define NL 4
#define EPSV 1e-5f
#define S_U1 8
#define S_U2 4
#define NBMSG 512      // msg persistent blocks (2/CU, LDS-limited)
#define MSG_LDS 75776  // 8K We + 32K W2 + 8*4352 zeb

using f32x4  = __attribute__((ext_vector_type(4))) float;
using bf16x8 = __attribute__((ext_vector_type(8))) short;
typedef _Float16 f16x8 __attribute__((ext_vector_type(8)));

#define MFMAB(a, b, c) __builtin_amdgcn_mfma_f32_16x16x32_bf16((a), (b), (c), 0, 0, 0)
#define MFMAH(a, b, c) __builtin_amdgcn_mfma_f32_16x16x32_f16((a), (b), (c), 0, 0, 0)

union H8 { int4 i; unsigned int u[4]; f16x8 f; };

__device__ __forceinline__ unsigned short f2bf(float x) {
  unsigned int u = __float_as_uint(x);
  u = (u + 0x7FFFu + ((u >> 16) & 1u)) >> 16;  // RNE
  return (unsigned short)u;
}

__device__ __forceinline__ unsigned short f2h(float x) {
  return __half_as_ushort(__float2half(x));
}

__device__ __forceinline__ float h2f(unsigned short x) {
  return __half2float(__ushort_as_half(x));
}

// packed f16 math via VOP3P inline asm (validated R9-R13)
__device__ __forceinline__ unsigned int pk_add(unsigned int a, unsigned int b) {
  unsigned int r;
  asm("v_pk_add_f16 %0, %1, %2" : "=v"(r) : "v"(a), "v"(b));
  return r;
}
__device__ __forceinline__ unsigned int pk_relu(unsigned int a) {
  unsigned int r;
  asm("v_pk_max_f16 %0, %1, 0" : "=v"(r) : "v"(a));
  return r;
}

// CONTRACT (m104/m108): LDS dest = wave-uniform base + lane*16. Call sites MUST
// use idx = i*blockDim + tid so consecutive lanes write consecutive granules.
__device__ __forceinline__ void gload_lds16(const void* gp, void* lp) {
  typedef __attribute__((address_space(1))) unsigned int as1_u32;
  typedef __attribute__((address_space(3))) unsigned int as3_u32;
  __builtin_amdgcn_global_load_lds((as1_u32*)(unsigned long long)gp,
                                   (as3_u32*)(unsigned int)(unsigned long long)lp,
                                   16, 0, 0);
}

__device__ __forceinline__ bf16x8 pack8(float4 a, float4 b) {
  bf16x8 o;
  o[0] = (short)f2bf(a.x); o[1] = (short)f2bf(a.y);
  o[2] = (short)f2bf(a.z); o[3] = (short)f2bf(a.w);
  o[4] = (short)f2bf(b.x); o[5] = (short)f2bf(b.y);
  o[6] = (short)f2bf(b.z); o[7] = (short)f2bf(b.w);
  return o;
}

__device__ __forceinline__ int4 pack8h(float4 a, float4 b) {
  int4 o;
  o.x = (int)((unsigned)f2h(a.x) | ((unsigned)f2h(a.y) << 16));
  o.y = (int)((unsigned)f2h(a.z) | ((unsigned)f2h(a.w) << 16));
  o.z = (int)((unsigned)f2h(b.x) | ((unsigned)f2h(b.y) << 16));
  o.w = (int)((unsigned)f2h(b.z) | ((unsigned)f2h(b.w) << 16));
  return o;
}

// ---------------- prep kernels (validated) ----------------
__global__ void wprep_kernel(const float* __restrict__ W, const float* __restrict__ g,
                             const float* __restrict__ v, unsigned short* __restrict__ out,
                             int K, int S, int total) {
  int idx = blockIdx.x * 256 + threadIdx.x;
  if (idx >= total) return;
  int e = idx & 7, l0 = (idx >> 3) & 63, f = idx >> 9;
  int n = f & 7, sf = f >> 3, s = sf % S, l = sf / S;
  int k = s * 32 + ((l0 >> 4) << 3) + e;
  int c = (n << 4) + (l0 & 15);
  float val = 0.f;
  if (k < K) {
    float sc = g[l * D + c] * rsqrtf(v[l * D + c] + EPSV);
    val = W[((size_t)(l * K + k)) * D + c] * sc;
  }
  out[idx] = f2bf(val);
}

__global__ void wprep16_kernel(const float* __restrict__ W, const float* __restrict__ g,
                               const float* __restrict__ v, unsigned short* __restrict__ out,
                               int Ktot, int ko, int Kact, int S, int total) {
  int idx = blockIdx.x * 256 + threadIdx.x;
  if (idx >= total) return;
  int e = idx & 7, l0 = (idx >> 3) & 63, f = idx >> 9;
  int n = f & 7, sf = f >> 3, s = sf % S, l = sf / S;
  int k = s * 32 + ((l0 >> 4) << 3) + e;
  int c = (n << 4) + (l0 & 15);
  float val = 0.f;
  if (k < Kact) {
    float sc = g[l * D + c] * rsqrtf(v[l * D + c] + EPSV);
    val = W[((size_t)(l * Ktot + ko + k)) * D + c] * sc;
  }
  out[idx] = f2h(val);
}

__global__ void wprepz_kernel(const float* __restrict__ W1, const float* __restrict__ g,
                              const float* __restrict__ v, unsigned short* __restrict__ out,
                              int total) {
  int idx = blockIdx.x * 256 + threadIdx.x;
  if (idx >= total) return;
  int e = idx & 7, l0 = (idx >> 3) & 63, f = idx >> 9;
  int n = f & 15, sf = f >> 4, s = sf & 3, l = sf >> 2;
  int k = s * 32 + ((l0 >> 4) << 3) + e;
  int c = ((n & 7) << 4) + (l0 & 15);
  int row = (n < 8) ? k : 128 + k;
  float sc = g[l * D + c] * rsqrtf(v[l * D + c] + EPSV);
  float val = W1[((size_t)(l * 272 + row)) * D + c] * sc;
  out[idx] = f2bf(val);
}

// Win frag-order, K=64 (S=2), no BN fold
__global__ void wprepx_kernel(const float* __restrict__ Win, unsigned short* __restrict__ out) {
  int idx = blockIdx.x * 256 + threadIdx.x;
  if (idx >= 8192) return;
  int e = idx & 7, l0 = (idx >> 3) & 63, f = idx >> 9;
  int n = f & 7, s = f >> 3;
  int k = s * 32 + ((l0 >> 4) << 3) + e;
  int c = (n << 4) + (l0 & 15);
  out[idx] = f2bf(Win[k * D + c]);
}

__global__ void cvtx_kernel(const float* __restrict__ x, unsigned short* __restrict__ xbf, int n8) {
  int idx = blockIdx.x * 256 + threadIdx.x;
  if (idx >= n8) return;
  float4 a = reinterpret_cast<const float4*>(x)[idx * 2];
  float4 b = reinterpret_cast<const float4*>(x)[idx * 2 + 1];
  reinterpret_cast<bf16x8*>(xbf)[idx] = pack8(a, b);
}

__global__ void bprep_kernel(const float* __restrict__ b, const float* __restrict__ g,
                             const float* __restrict__ be, const float* __restrict__ m,
                             const float* __restrict__ v, float* __restrict__ out) {
  int idx = blockIdx.x * 256 + threadIdx.x;
  if (idx >= NL * D) return;
  float s = g[idx] * rsqrtf(v[idx] + EPSV);
  out[idx] = (b[idx] - m[idx]) * s + be[idx];
}

// ---------------- fused xproj + layer-0 z-GEMM (validated R12/R13) ----------------
__global__ __launch_bounds__(256)
void xz_kernel(const unsigned short* __restrict__ xbf,
               const unsigned short* __restrict__ Wxf,
               const float* __restrict__ bin,
               const unsigned short* __restrict__ Wzf,
               const float* __restrict__ b1,
               float* __restrict__ h,
               unsigned short* __restrict__ hbf,
               unsigned short* __restrict__ zds, int N) {
  __shared__ unsigned short m1ls[4][16 * 128];
  const int tid = threadIdx.x, wid = tid >> 6, lane = tid & 63, g = lane >> 4, r = lane & 15;
  const int nbase = blockIdx.x * 64;
  const int nr = nbase + wid * 16 + r;
  const int ar = (nr < N) ? nr : (N - 1);

  bf16x8 aX[2];
#pragma unroll
  for (int s = 0; s < 2; ++s)
    aX[s] = *reinterpret_cast<const bf16x8*>(xbf + (size_t)ar * 64 + s * 32 + g * 8);

  f32x4 acc[8];
#pragma unroll
  for (int n = 0; n < 8; ++n)
#pragma unroll
    for (int q = 0; q < 4; ++q) acc[n][q] = 0.f;
#pragma unroll
  for (int s = 0; s < 2; ++s)
#pragma unroll
    for (int n = 0; n < 8; ++n)
      acc[n] = MFMAB(aX[s], *reinterpret_cast<const bf16x8*>(Wxf + (((s * 8 + n) << 9) + (lane << 3))), acc[n]);

  float bia[8];
#pragma unroll
  for (int n = 0; n < 8; ++n) bia[n] = bin[n * 16 + r];

  unsigned short* m1w = &m1ls[wid][0];
#pragma unroll
  for (int j = 0; j < 4; ++j) {
    int node = nbase + wid * 16 + g * 4 + j;
    if (node < N) {
#pragma unroll
      for (int n = 0; n < 8; ++n) {
        int col = n * 16 + r;
        float hv = acc[n][j] + bia[n];
        h[(size_t)node * D + col] = hv;
        unsigned short hb = f2bf(hv);
        hbf[(size_t)node * D + col] = hb;
        int row0 = g * 4 + j;
        m1w[row0 * 128 + (col ^ ((row0 & 7) << 3))] = hb;
      }
    }
  }

  bf16x8 aZ[4];
#pragma unroll
  for (int s = 0; s < 4; ++s) {
    int k0 = s * 32 + g * 8;
    aZ[s] = *reinterpret_cast<const bf16x8*>(m1w + r * 128 + (k0 ^ ((r & 7) << 3)));
  }
  float bz[8];
#pragma unroll
  for (int n = 0; n < 8; ++n) bz[n] = b1[n * 16 + r];
#pragma unroll
  for (int half = 0; half < 2; ++half) {
    f32x4 zacc[8];
#pragma unroll
    for (int n = 0; n < 8; ++n)
#pragma unroll
      for (int q = 0; q < 4; ++q) zacc[n][q] = 0.f;
#pragma unroll
    for (int s = 0; s < 4; ++s)
#pragma unroll
      for (int n = 0; n < 8; ++n)
        zacc[n] = MFMAB(aZ[s], *reinterpret_cast<const bf16x8*>(Wzf + (((s * 16 + half * 8 + n) << 9) + (lane << 3))), zacc[n]);
#pragma unroll
    for (int n = 0; n < 8; ++n)
#pragma unroll
      for (int j = 0; j < 4; ++j) {
        int node = nbase + wid * 16 + g * 4 + j;
        if (node < N) {
          float v = zacc[n][j] + (half == 0 ? bz[n] : 0.f);
          zds[(size_t)node * 256 + (half * 8 + n) * 16 + r] = f2h(v);
        }
      }
  }
}

// ---------------- counting sort of edges by dst (validated) ----------------
__global__ void hist_kernel(const int* __restrict__ eidx, int* __restrict__ hist, int E) {
  int e = blockIdx.x * 256 + threadIdx.x;
  if (e < E) atomicAdd(&hist[eidx[E + e]], 1);
}

__global__ void scan1_kernel(const int* __restrict__ hist, int* __restrict__ bsum, int N) {
  __shared__ int sb[256];
  int i = blockIdx.x * 256 + threadIdx.x;
  sb[threadIdx.x] = (i < N) ? hist[i] : 0;
  __syncthreads();
  for (int d = 128; d > 0; d >>= 1) {
    if (threadIdx.x < d) sb[threadIdx.x] += sb[threadIdx.x + d];
    __syncthreads();
  }
  if (threadIdx.x == 0) bsum[blockIdx.x] = sb[0];
}

__global__ void scan2_kernel(int* __restrict__ bsum, int nb) {
  __shared__ int sb[2][256];
  int t = threadIdx.x;
  int v = (t < nb) ? bsum[t] : 0;
  int p = 0;
  sb[0][t] = v; __syncthreads();
#pragma unroll
  for (int d = 1; d < 256; d <<= 1) {
    int nv = sb[p][t] + ((t >= d) ? sb[p][t - d] : 0);
    sb[p ^ 1][t] = nv; p ^= 1;
    __syncthreads();
  }
  if (t < nb) bsum[t] = sb[p][t] - v;
}

__global__ void scan3_kernel(int* __restrict__ hist, const int* __restrict__ bsum, int N) {
  __shared__ int sb[2][256];
  int i = blockIdx.x * 256 + threadIdx.x, t = threadIdx.x;
  int v = (i < N) ? hist[i] : 0;
  int p = 0;
  sb[0][t] = v; __syncthreads();
#pragma unroll
  for (int d = 1; d < 256; d <<= 1) {
    int nv = sb[p][t] + ((t >= d) ? sb[p][t - d] : 0);
    sb[p ^ 1][t] = nv; p ^= 1;
    __syncthreads();
  }
  if (i < N) hist[i] = sb[p][t] - v + bsum[blockIdx.x];
}

__global__ void scatter_kernel(const int* __restrict__ eidx, int* __restrict__ cursor,
                               int* __restrict__ dstS, int* __restrict__ srcS,
                               int* __restrict__ eidS, int E) {
  int e = blockIdx.x * 256 + threadIdx.x;
  if (e >= E) return;
  int d = eidx[E + e];
  int pos = atomicAdd(&cursor[d], 1);
  dstS[pos] = d;
  srcS[pos] = eidx[e];
  eidS[pos] = e;
}
// NOTE: after scatter, cursor[v] == END offset of segment v (CSR).

__global__ void eperm_kernel(const float* __restrict__ eattr, const int* __restrict__ eidS,
                             unsigned short* __restrict__ ebfS, int E) {
  int i = blockIdx.x * 256 + threadIdx.x;
  if (i >= E) return;
  const float4* src = reinterpret_cast<const float4*>(eattr + (size_t)eidS[i] * DE);
  *reinterpret_cast<int4*>(ebfS + (size_t)i * DE) = pack8h(src[0], src[1]);
  *reinterpret_cast<int4*>(ebfS + (size_t)i * DE + 8) = pack8h(src[2], src[3]);
}

// ---------------- fused message kernel (R13 two-phase + index prefetch) ----------------
__global__ __launch_bounds__(512, 4)
void msg_kernel(const unsigned short* __restrict__ zds,
                const unsigned short* __restrict__ ebfS,
                const int* __restrict__ dstS,
                const int* __restrict__ srcS,
                const unsigned short* __restrict__ Wef,   // f16 frag, 8KB
                const unsigned short* __restrict__ W2f,   // f16 frag, 32KB
                const float* __restrict__ b2,
                unsigned short* __restrict__ msgb, int E, int T) {
  extern __shared__ char smem[];
  unsigned short* Wels = (unsigned short*)smem;            // We: [0, 4096) shorts
  unsigned short* W2ls = (unsigned short*)(smem + 8192);   // W2: 16384 shorts
  const int tid = threadIdx.x;
  const int wid = tid >> 6, lane = tid & 63, g = lane >> 4, r = lane & 15;
  unsigned short* zeb = (unsigned short*)(smem + 40960 + wid * 4352);  // 16x136 shorts/wave

  gload_lds16(Wef + ((size_t)tid << 3), smem + (tid << 4));
#pragma unroll
  for (int i = 0; i < 4; ++i) {
    int idx = i * 512 + tid;
    gload_lds16(W2f + ((size_t)idx << 3), smem + 8192 + (idx << 4));
  }

  float bia2[8];
#pragma unroll
  for (int n = 0; n < 8; ++n) bia2[n] = b2[n * 16 + r];

  const int t0 = (int)(((long long)blockIdx.x * T) / gridDim.x);
  const int t1 = (int)(((long long)(blockIdx.x + 1) * T) / gridDim.x);

  __syncthreads();

  // prefetch first tile's indices (removes index-load from the per-tile chain)
  int ii_n = 0, dst_n = 0, src_n = 0;
  if (t0 < t1) {
    ii_n = min(t0 * 128 + wid * 16 + r, E - 1);
    dst_n = dstS[ii_n]; src_n = srcS[ii_n];
  }

  for (int t = t0; t < t1; ++t) {
    const int ii0 = ii_n;
    const int dst0 = dst_n, src0 = src_n;

    // issue random gathers for current tile immediately
    H8 zd[4], zs[4];
#pragma unroll
    for (int s = 0; s < 4; ++s) {
      zd[s].i = *reinterpret_cast<const int4*>(zds + (size_t)dst0 * 256 + s * 32 + g * 8);
      zs[s].i = *reinterpret_cast<const int4*>(zds + (size_t)src0 * 256 + 128 + s * 32 + g * 8);
    }

    // prefetch next tile's indices (latency hidden under this tile's compute)
    if (t + 1 < t1) {
      ii_n = min((t + 1) * 128 + wid * 16 + r, E - 1);
      dst_n = dstS[ii_n]; src_n = srcS[ii_n];
    }

    // ze = We^T eattr (A rows = 16 edges)
    H8 aE;
    aE.i = make_int4(0, 0, 0, 0);
    if (g < 2) aE.i = *reinterpret_cast<const int4*>(ebfS + (size_t)ii0 * DE + g * 8);
    f32x4 ze[8];
#pragma unroll
    for (int n = 0; n < 8; ++n)
#pragma unroll
      for (int q = 0; q < 4; ++q) ze[n][q] = 0.f;
#pragma unroll
    for (int n = 0; n < 8; ++n) {
      f16x8 b = *reinterpret_cast<const f16x8*>(Wels + (n << 9) + (lane << 3));
      ze[n] = MFMAH(aE.f, b, ze[n]);
    }

    // C-frag (row=edge g*4+j, chan n*16+r) -> [16 rows][136-short rows] LDS
#pragma unroll
    for (int n = 0; n < 8; ++n)
#pragma unroll
      for (int j = 0; j < 4; ++j) {
        int row = g * 4 + j;
        zeb[row * 136 + ((n * 2 + (r >> 3)) << 3) + (r & 7)] = f2h(ze[n][j]);
      }

    f32x4 c[8];
#pragma unroll
    for (int n = 0; n < 8; ++n)
#pragma unroll
      for (int q = 0; q < 4; ++q) c[n][q] = 0.f;

    // GEMM2: A-frag row=r, chans k=s*32+g*8 -> granule s*4+g
#pragma unroll
    for (int s = 0; s < 4; ++s) {
      H8 zeA, m;
      zeA.i = *reinterpret_cast<const int4*>(zeb + r * 136 + ((s * 4 + g) << 3));
#pragma unroll
      for (int w = 0; w < 4; ++w)
        m.u[w] = pk_relu(pk_add(pk_add(zd[s].u[w], zs[s].u[w]), zeA.u[w]));
      __builtin_amdgcn_s_setprio(1);
#pragma unroll
      for (int n = 0; n < 8; ++n) {
        f16x8 b = *reinterpret_cast<const f16x8*>(W2ls + ((s * 8 + n) << 9) + (lane << 3));
        c[n] = MFMAH(m.f, b, c[n]);
      }
      __builtin_amdgcn_s_setprio(0);
    }

    // epilogue: bias+relu -> f16 quad store; q = t*32 + wid*4 + g
#pragma unroll
    for (int n = 0; n < 8; ++n) {
      unsigned int lo = (unsigned)f2h(fmaxf(c[n][0] + bia2[n], 0.f))
                      | ((unsigned)f2h(fmaxf(c[n][1] + bia2[n], 0.f)) << 16);
      unsigned int hi = (unsigned)f2h(fmaxf(c[n][2] + bia2[n], 0.f))
                      | ((unsigned)f2h(fmaxf(c[n][3] + bia2[n], 0.f)) << 16);
      size_t addr8 = ((((size_t)t * 32 + wid * 4 + g) * 8 + n) * 16) + r;
      uint2 pk; pk.x = lo; pk.y = hi;
      *reinterpret_cast<uint2*>(msgb + addr8 * 4) = pk;
    }
  }
}

// ---------------- CSR segment reduce (validated R12/R13; grid doubled) ----------------
__global__ __launch_bounds__(256)
void reduce_kernel(const unsigned short* __restrict__ msgb,
                   const int* __restrict__ csr_end,
                   unsigned short* __restrict__ aggbf, int N) {
  const int tid = threadIdx.x, wid = tid >> 6, lane = tid & 63;
  const int er = lane >> 4, cg = lane & 15;
  for (int v = blockIdx.x * 4 + wid; v < N; v += gridDim.x * 4) {
    const int s = (v == 0) ? 0 : csr_end[v - 1];
    const int e = csr_end[v];
    float a[8];
#pragma unroll
    for (int n = 0; n < 8; ++n) a[n] = 0.f;
    const int qe = (e + 3) >> 2;
    for (int qb = (s >> 2); qb < qe; qb += 4) {
      int q = qb + er;
      if (q < qe) {
        size_t base8 = (size_t)q * 128 + cg;
        int p0 = 4 * q;
#pragma unroll
        for (int n = 0; n < 8; ++n) {
          uint2 d = *reinterpret_cast<const uint2*>(msgb + (base8 + (size_t)n * 16) * 4);
          float v0 = h2f((unsigned short)(d.x & 0xffff));
          float v1 = h2f((unsigned short)(d.x >> 16));
          float v2 = h2f((unsigned short)(d.y & 0xffff));
          float v3 = h2f((unsigned short)(d.y >> 16));
          a[n] += ((p0 >= s && p0 < e) ? v0 : 0.f)
                + ((p0 + 1 >= s && p0 + 1 < e) ? v1 : 0.f)
                + ((p0 + 2 >= s && p0 + 2 < e) ? v2 : 0.f)
                + ((p0 + 3 >= s && p0 + 3 < e) ? v3 : 0.f);
        }
      }
    }
#pragma unroll
    for (int n = 0; n < 8; ++n) {
      a[n] += __shfl_xor(a[n], 16);
      a[n] += __shfl_xor(a[n], 32);
    }
    if (er == 0) {
#pragma unroll
      for (int n = 0; n < 8; ++n)
        aggbf[(size_t)v * 128 + n * 16 + cg] = f2bf(a[n]);
    }
  }
}

// ---------------- node update + fused next-layer z-GEMM (R13 config: (256,3), 50us) ----------------
__global__ __launch_bounds__(256, 3)
void node_kernel(const unsigned short* __restrict__ hbf,
                 const unsigned short* __restrict__ aggbf,
                 const unsigned short* __restrict__ W1f,
                 const unsigned short* __restrict__ W2f,
                 const float* __restrict__ b1,
                 const float* __restrict__ b2,
                 float* __restrict__ h,
                 unsigned short* __restrict__ hbfo,
                 const unsigned short* __restrict__ Wzf,
                 const float* __restrict__ b1n,
                 unsigned short* __restrict__ zds, int N) {
  __shared__ unsigned short m1ls[4][16 * 128];

  const int tid = threadIdx.x, wid = tid >> 6, lane = tid & 63, g = lane >> 4, r = lane & 15;
  const int nbase = blockIdx.x * 64;
  const int nr0 = nbase + wid * 16 + r;
  const int ar0 = (nr0 < N) ? nr0 : (N - 1);

  bf16x8 aH0[4], aG0[4];
#pragma unroll
  for (int s = 0; s < 4; ++s) {
    aH0[s] = *reinterpret_cast<const bf16x8*>(hbf + (size_t)ar0 * D + s * 32 + g * 8);
    aG0[s] = *reinterpret_cast<const bf16x8*>(aggbf + (size_t)ar0 * D + s * 32 + g * 8);
  }

  // hoisted epilogue h-row f32 loads (overlap with U1/U2 MFMA)
  float hv[4][8];
#pragma unroll
  for (int j = 0; j < 4; ++j) {
    int node = nbase + wid * 16 + g * 4 + j;
    int an = (node < N) ? node : (N - 1);
#pragma unroll
    for (int n = 0; n < 8; ++n)
      hv[j][n] = h[(size_t)an * D + n * 16 + r];
  }

  float bia1[8], bia2[8];
#pragma unroll
  for (int n = 0; n < 8; ++n) { bia1[n] = b1[n * 16 + r]; bia2[n] = b2[n * 16 + r]; }

  f32x4 acc0[8];
#pragma unroll
  for (int n = 0; n < 8; ++n)
#pragma unroll
    for (int q = 0; q < 4; ++q) acc0[n][q] = 0.f;

#pragma unroll
  for (int s = 0; s < S_U1; ++s) {
    bf16x8 a0 = (s < 4) ? aH0[s & 3] : aG0[(s - 4) & 3];
#pragma unroll
    for (int n = 0; n < 8; ++n) {
      bf16x8 b = *reinterpret_cast<const bf16x8*>(W1f + (((s * 8 + n) << 9) + (lane << 3)));
      acc0[n] = MFMAB(a0, b, acc0[n]);
    }
  }

  unsigned short* m1w = &m1ls[wid][0];
#pragma unroll
  for (int n = 0; n < 8; ++n)
#pragma unroll
    for (int j = 0; j < 4; ++j) {
      int col = n * 16 + r;
      int row0 = g * 4 + j;
      m1w[row0 * 128 + (col ^ ((row0 & 7) << 3))] = f2bf(fmaxf(acc0[n][j] + bia1[n], 0.f));
    }

  f32x4 c0[8];
#pragma unroll
  for (int n = 0; n < 8; ++n)
#pragma unroll
    for (int q = 0; q < 4; ++q) c0[n][q] = 0.f;

#pragma unroll
  for (int s = 0; s < S_U2; ++s) {
    int k0 = s * 32 + g * 8;
    bf16x8 a0 = *reinterpret_cast<const bf16x8*>(m1w + r * 128 + (k0 ^ ((r & 7) << 3)));
#pragma unroll
    for (int n = 0; n < 8; ++n) {
      bf16x8 b = *reinterpret_cast<const bf16x8*>(W2f + (((s * 8 + n) << 9) + (lane << 3)));
      c0[n] = MFMAB(a0, b, c0[n]);
    }
  }

#pragma unroll
  for (int j = 0; j < 4; ++j) {
    int node = nbase + wid * 16 + g * 4 + j;
    if (node < N) {
#pragma unroll
      for (int n = 0; n < 8; ++n) {
        int col = n * 16 + r;
        float hvnew = hv[j][n] + fmaxf(c0[n][j] + bia2[n], 0.f);
        h[(size_t)node * D + col] = hvnew;
        unsigned short hb = f2bf(hvnew);
        hbfo[(size_t)node * D + col] = hb;
        int row0 = g * 4 + j;
        m1w[row0 * 128 + (col ^ ((row0 & 7) << 3))] = hb;
      }
    }
  }

  if (Wzf != nullptr) {
    bf16x8 aZ[4];
#pragma unroll
    for (int s = 0; s < 4; ++s) {
      int k0 = s * 32 + g * 8;
      aZ[s] = *reinterpret_cast<const bf16x8*>(m1w + r * 128 + (k0 ^ ((r & 7) << 3)));
    }
    float bz[8];
#pragma unroll
    for (int n = 0; n < 8; ++n) bz[n] = b1n[n * 16 + r];
#pragma unroll
    for (int half = 0; half < 2; ++half) {
      f32x4 zacc[8];
#pragma unroll
      for (int n = 0; n < 8; ++n)
#pragma unroll
        for (int q = 0; q < 4; ++q) zacc[n][q] = 0.f;
#pragma unroll
      for (int s = 0; s < 4; ++s)
#pragma unroll
        for (int n = 0; n < 8; ++n)
          zacc[n] = MFMAB(aZ[s], *reinterpret_cast<const bf16x8*>(Wzf + (((s * 16 + half * 8 + n) << 9) + (lane << 3))), zacc[n]);
#pragma unroll
      for (int n = 0; n < 8; ++n)
#pragma unroll
        for (int j = 0; j < 4; ++j) {
          int node = nbase + wid * 16 + g * 4 + j;
          if (node < N) {
            float v = zacc[n][j] + (half == 0 ? bz[n] : 0.f);
            zds[(size_t)node * 256 + (half * 8 + n) * 16 + r] = f2h(v);
          }
        }
    }
  }
}

extern "C" void kernel_launch(void* const* d_in, const int* in_sizes, int n_in,
                              void* d_out, int out_size, void* d_ws, size_t ws_size,
                              hipStream_t stream) {
  const float* x     = (const float*)d_in[0];
  const int*   eidx  = (const int*)d_in[1];
  const float* eattr = (const float*)d_in[2];
  const float* Win   = (const float*)d_in[3];
  const float* bin   = (const float*)d_in[4];
  const float* Wm1 = (const float*)d_in[5];  const float* bm1 = (const float*)d_in[6];
  const float* gm1 = (const float*)d_in[7];  const float* bem1 = (const float*)d_in[8];
  const float* mm1 = (const float*)d_in[9];  const float* vm1 = (const float*)d_in[10];
  const float* Wm2 = (const float*)d_in[11]; const float* bm2 = (const float*)d_in[12];
  const float* gm2 = (const float*)d_in[13]; const float* bem2 = (const float*)d_in[14];
  const float* mm2 = (const float*)d_in[15]; const float* vm2 = (const float*)d_in[16];
  const float* Wu1 = (const float*)d_in[17]; const float* bu1 = (const float*)d_in[18];
  const float* gu1 = (const float*)d_in[19]; const float* beu1 = (const float*)d_in[20];
  const float* mu1 = (const float*)d_in[21]; const float* vu1 = (const float*)d_in[22];
  const float* Wu2 = (const float*)d_in[23]; const float* bu2 = (const float*)d_in[24];
  const float* gu2 = (const float*)d_in[25]; const float* beu2 = (const float*)d_in[26];
  const float* mu2 = (const float*)d_in[27]; const float* vu2 = (const float*)d_in[28];

  const int N = in_sizes[0] / 64;
  const int E = in_sizes[1] / 2;
  float* h = (float*)d_out;

  const int T = (E + 127) / 128;             // msg tiles (128 edges each)
  const size_t Epad = (size_t)T * 128;       // msgb rows

  // workspace layout (16B-aligned slabs), ~210 MB
  char* ws = (char*)d_ws;
  size_t off = 0;
  unsigned short* aggbf = (unsigned short*)(ws + off); off += (size_t)N * D * 2;
  unsigned short* hbf   = (unsigned short*)(ws + off); off += (size_t)N * D * 2;
  unsigned short* zds   = (unsigned short*)(ws + off); off += (size_t)N * 256 * 2;
  unsigned short* xbf   = (unsigned short*)(ws + off); off += (size_t)N * 64 * 2;
  unsigned short* ebfS  = (unsigned short*)(ws + off); off += (size_t)E * DE * 2;
  int* dstS = (int*)(ws + off);                        off += (size_t)E * 4;
  int* srcS = (int*)(ws + off);                        off += (size_t)E * 4;
  int* eidS = (int*)(ws + off);                        off += (size_t)E * 4;
  int* hist = (int*)(ws + off);                        off += ((size_t)N * 4 + 15) & ~15ull;
  int* bsum = (int*)(ws + off);                        off += 1024;
  unsigned short* Wef   = (unsigned short*)(ws + off); off += (size_t)NL * 4096 * 2;
  unsigned short* W2f16 = (unsigned short*)(ws + off); off += (size_t)NL * 16384 * 2;
  unsigned short* Wzf   = (unsigned short*)(ws + off); off += (size_t)NL * 32768 * 2;
  unsigned short* Wu1f  = (unsigned short*)(ws + off); off += (size_t)NL * S_U1 * 4096 * 2;
  unsigned short* Wu2f  = (unsigned short*)(ws + off); off += (size_t)NL * S_U2 * 4096 * 2;
  unsigned short* Wxf   = (unsigned short*)(ws + off); off += (size_t)8192 * 2;
  float* bm1f = (float*)(ws + off); off += (size_t)NL * D * 4;
  float* bm2f = (float*)(ws + off); off += (size_t)NL * D * 4;
  float* bu1f = (float*)(ws + off); off += (size_t)NL * D * 4;
  float* bu2f = (float*)(ws + off); off += (size_t)NL * D * 4;
  unsigned short* msgb = (unsigned short*)(ws + off);  off += Epad * 128 * 2;  // 128 MB m2
  if (off > ws_size) return;

  (void)hipFuncSetAttribute(reinterpret_cast<const void*>(msg_kernel),
                            hipFuncAttributeMaxDynamicSharedMemorySize, MSG_LDS);

  // ---- prep: folded frag-ordered weights + biases ----
  {
    int tWe = NL * 4096, tW2 = NL * 16384, tWz = NL * 32768;
    int tU1 = NL * S_U1 * 4096, tU2 = NL * S_U2 * 4096;
    wprep16_kernel<<<(tWe + 255) / 256, 256, 0, stream>>>(Wm1, gm1, vm1, Wef, 272, 256, 16, 1, tWe);
    wprep16_kernel<<<(tW2 + 255) / 256, 256, 0, stream>>>(Wm2, gm2, vm2, W2f16, 128, 0, 128, 4, tW2);
    wprepz_kernel<<<(tWz + 255) / 256, 256, 0, stream>>>(Wm1, gm1, vm1, Wzf, tWz);
    wprep_kernel<<<(tU1 + 255) / 256, 256, 0, stream>>>(Wu1, gu1, vu1, Wu1f, 2 * D, S_U1, tU1);
    wprep_kernel<<<(tU2 + 255) / 256, 256, 0, stream>>>(Wu2, gu2, vu2, Wu2f, D, S_U2, tU2);
    wprepx_kernel<<<32, 256, 0, stream>>>(Win, Wxf);
    cvtx_kernel<<<(N * 8 + 255) / 256, 256, 0, stream>>>(x, xbf, N * 8);
    bprep_kernel<<<2, 256, 0, stream>>>(bm1, gm1, bem1, mm1, vm1, bm1f);
    bprep_kernel<<<2, 256, 0, stream>>>(bm2, gm2, bem2, mm2, vm2, bm2f);
    bprep_kernel<<<2, 256, 0, stream>>>(bu1, gu1, beu1, mu1, vu1, bu1f);
    bprep_kernel<<<2, 256, 0, stream>>>(bu2, gu2, beu2, mu2, vu2, bu2f);
  }

  // ---- counting sort of edges by dst (hist becomes CSR end offsets) ----
  {
    const int NB_H = (N + 255) / 256;
    (void)hipMemsetAsync(hist, 0, (size_t)N * 4, stream);
    hist_kernel<<<(E + 255) / 256, 256, 0, stream>>>(eidx, hist, E);
    scan1_kernel<<<NB_H, 256, 0, stream>>>(hist, bsum, N);
    scan2_kernel<<<1, 256, 0, stream>>>(bsum, NB_H);
    scan3_kernel<<<NB_H, 256, 0, stream>>>(hist, bsum, N);
    scatter_kernel<<<(E + 255) / 256, 256, 0, stream>>>(eidx, hist, dstS, srcS, eidS, E);
    eperm_kernel<<<(E + 255) / 256, 256, 0, stream>>>(eattr, eidS, ebfS, E);
  }

  // ---- fused input projection + layer-0 z (MFMA) ----
  const int nblocks = (N + 63) / 64;
  xz_kernel<<<nblocks, 256, 0, stream>>>(xbf, Wxf, bin, Wzf, bm1f, h, hbf, zds, N);

  // ---- layers ----
  for (int l = 0; l < NL; ++l) {
    msg_kernel<<<NBMSG, 512, MSG_LDS, stream>>>(zds, ebfS, dstS, srcS,
                                                Wef + (size_t)l * 4096,
                                                W2f16 + (size_t)l * 16384,
                                                bm2f + l * D, msgb, E, T);
    reduce_kernel<<<4096, 256, 0, stream>>>(msgb, hist, aggbf, N);
    const unsigned short* WzNext = (l < NL - 1) ? (Wzf + (size_t)(l + 1) * 32768) : nullptr;
    const float* b1Next = bm1f + ((l < NL - 1) ? (l + 1) : 0) * D;
    node_kernel<<<nblocks, 256, 0, stream>>>(hbf, aggbf,
                                             Wu1f + (size_t)l * S_U1 * 4096,
                                             Wu2f + (size_t)l * S_U2 * 4096,
                                             bu1f + l * D, bu2f + l * D, h, hbf,
                                             WzNext, b1Next, zds, N);
  }
}